// Round 6
// baseline (298.702 us; speedup 1.0000x reference)
//
#include <hip/hip_runtime.h>
#include <cstdio>
#include <cstdint>

// ---------------------------------------------------------------------------
// Transformer-XL relative MHA, MI355X/gfx950.  B=16 T=512 D=512 H=8 hd=64.
// Round 6: LDS staged in MFMA-fragment order (g2l16 lane-linear == A/B frag
// layout -> ds_read_b128 fully linear, zero bank conflicts), balanced proj
// grid (v 64x64 tiles first, then qk/p 128x128; 16 KB LDS everywhere),
// out_gemm 64x64 tiles -> 1024 blocks. Flash unchanged from R5 (packed
// fragments, barrier-free, fixed-max softmax, nsplit=2).
// Precision: logit path bf16 (softmax attenuates); v/PV/out split-bf16.
// ---------------------------------------------------------------------------

typedef short s16x8 __attribute__((ext_vector_type(8)));
typedef float f32x4 __attribute__((ext_vector_type(4)));
typedef unsigned short u16x4 __attribute__((ext_vector_type(4)));

#define CSCALE 0.1803368801111204f  // log2(e)/8

#if __has_builtin(__builtin_amdgcn_exp2f)
#define EXP2(x) __builtin_amdgcn_exp2f(x)
#else
#define EXP2(x) exp2f(x)
#endif

__device__ __forceinline__ unsigned short f2bf(float f) {  // RNE
  unsigned int u = __builtin_bit_cast(unsigned int, f);
  unsigned int r = (u + 0x7FFFu + ((u >> 16) & 1u)) >> 16;
  return (unsigned short)r;
}
__device__ __forceinline__ unsigned short bftr(float f) {  // truncate
  return (unsigned short)(__builtin_bit_cast(unsigned int, f) >> 16);
}
__device__ __forceinline__ float bf2f(unsigned short h) {
  unsigned int u = ((unsigned int)h) << 16;
  return __builtin_bit_cast(float, u);
}

// async global->LDS, 16B/lane; LDS dest = wave-uniform base + lane*16
__device__ __forceinline__ void g2l16(const void* g, void* l) {
  __builtin_amdgcn_global_load_lds(
      (const __attribute__((address_space(1))) void*)g,
      (__attribute__((address_space(3))) void*)l, 16, 0, 0);
}

// ---------------- fused prep: ln + pe cast + weight casts ------------------
__global__ __launch_bounds__(256) void megaprep(
    const float* __restrict__ x, const float* __restrict__ g,
    const float* __restrict__ bb, unsigned short* __restrict__ xh,
    unsigned short* __restrict__ xl, const float* __restrict__ pe,
    unsigned short* __restrict__ ped, const float* __restrict__ Wq,
    const float* __restrict__ Wk, const float* __restrict__ Wp,
    const float* __restrict__ Wv, const float* __restrict__ Wo,
    const float* __restrict__ bq, const float* __restrict__ bk,
    unsigned short* __restrict__ wqk, unsigned short* __restrict__ wpm,
    unsigned short* __restrict__ wvh, unsigned short* __restrict__ wvl,
    unsigned short* __restrict__ woh, unsigned short* __restrict__ wol,
    float* __restrict__ bqk) {
  __shared__ float red[8];
  const int bid = blockIdx.x, tid = threadIdx.x;
  if (bid < 8192) {  // LayerNorm, one row/block
    const int wave = tid >> 6, lane = tid & 63;
    const float* xr = x + (size_t)bid * 512;
    float v0 = xr[tid], v1 = xr[tid + 256];
    float s = v0 + v1, ss = v0 * v0 + v1 * v1;
#pragma unroll
    for (int d = 1; d < 64; d <<= 1) {
      s += __shfl_xor(s, d, 64);
      ss += __shfl_xor(ss, d, 64);
    }
    if (lane == 0) { red[wave] = s; red[4 + wave] = ss; }
    __syncthreads();
    s = red[0] + red[1] + red[2] + red[3];
    ss = red[4] + red[5] + red[6] + red[7];
    const float mu = s * (1.0f / 512.0f);
    const float var = ss * (1.0f / 512.0f) - mu * mu;
    const float rstd = rsqrtf(var + 1e-5f);
#pragma unroll
    for (int i = 0; i < 2; i++) {
      int d = tid + i * 256;
      float v = (i == 0) ? v0 : v1;
      float xn = (v - mu) * rstd * g[d] + bb[d];
      unsigned short hi = f2bf(xn);
      xh[(size_t)bid * 512 + d] = hi;
      xl[(size_t)bid * 512 + d] = f2bf(xn - bf2f(hi));
    }
  } else if (bid < 16384) {  // pe cast x4 (pad rows -> 0)
    int e0 = (bid - 8192) * 1024 + tid * 4;
    u16x4 o = {0, 0, 0, 0};
    if (e0 < 16368 * 512) {
      float4 v = *(const float4*)(pe + e0);
      o[0] = f2bf(v.x); o[1] = f2bf(v.y); o[2] = f2bf(v.z); o[3] = f2bf(v.w);
    }
    *(u16x4*)(ped + e0) = o;
  } else {  // weights x4
    int idx = (bid - 16384) * 1024 + tid * 4;
    int region = idx >> 18, off = idx & 262143;
    const float* src = (region == 0)   ? Wq
                       : (region == 1) ? Wk
                       : (region == 2) ? Wp
                       : (region == 3) ? Wv
                                       : Wo;
    float4 w = *(const float4*)(src + off);
    float wv4[4] = {w.x, w.y, w.z, w.w};
    u16x4 hv, lv;
#pragma unroll
    for (int j = 0; j < 4; j++) {
      unsigned short h = f2bf(wv4[j]);
      hv[j] = h;
      lv[j] = f2bf(wv4[j] - bf2f(h));
    }
    if (region == 0) {
      *(u16x4*)(wqk + off) = hv;
    } else if (region == 1) {
      *(u16x4*)(wqk + 262144 + off) = hv;
    } else if (region == 2) {
      *(u16x4*)(wpm + off) = hv;
    } else if (region == 3) {
      *(u16x4*)(wvh + off) = hv;
      *(u16x4*)(wvl + off) = lv;
    } else {
      *(u16x4*)(woh + off) = hv;
      *(u16x4*)(wol + off) = lv;
    }
    if (idx < 1024) {
#pragma unroll
      for (int j = 0; j < 4; j++) {
        int ii = idx + j;
        bqk[ii] = (ii < 512) ? bq[ii] : bk[ii - 512];
      }
    }
  }
}

// ---------------- 128x128 GEMM body, BK=32, pairs=1, frag-packed LDS -------
// LDS: bA = 8 x 1KB fragment tiles (16 rows x 32 k, lane-linear), bB same.
// Wave w stages A tiles {2w,2w+1}, B tiles {2w,2w+1}. Every ds_read_b128 is
// base + lane*16 (conflict-free).
// mode 1: p packed epilogue;  mode 2: qc/qp/k packed epilogue.
__device__ __forceinline__ void gemm128_body(
    unsigned short* sm, int mode, int arow0, int m0e, int n0,
    const unsigned short* __restrict__ A, const unsigned short* __restrict__ B,
    const float* __restrict__ bias, void* __restrict__ O1, void* __restrict__ O2,
    void* __restrict__ O3, const float* __restrict__ cbv,
    const float* __restrict__ pbv) {
  unsigned short* bA = sm;          // 4096 shorts
  unsigned short* bB = sm + 4096;   // 4096 shorts
  const int tid = threadIdx.x, lane = tid & 63, wave = tid >> 6;
  const int wr = (wave >> 1) * 64, wc = (wave & 1) * 64;
  const int fr = lane & 15, hi2 = lane >> 4, fc = hi2 * 8;
  const int l15 = lane & 15, lq = lane >> 4;

  f32x4 fz = {0.f, 0.f, 0.f, 0.f};
  f32x4 acc[4][4];
#pragma unroll
  for (int i = 0; i < 4; i++)
#pragma unroll
    for (int j = 0; j < 4; j++) acc[i][j] = fz;

  // staging sources: lane -> (row = tile0 + l15, k = lq*8)
  const unsigned short* gA0 = A + (size_t)(arow0 + wave * 32 + l15) * 512 + lq * 8;
  const unsigned short* gA1 = gA0 + 16 * 512;
  const unsigned short* gB0 = B + (size_t)(n0 + wave * 32 + l15) * 512 + lq * 8;
  const unsigned short* gB1 = gB0 + 16 * 512;
  char* dA0 = (char*)bA + wave * 2048;
  char* dA1 = dA0 + 1024;
  char* dB0 = (char*)bB + wave * 2048;
  char* dB1 = dB0 + 1024;
  const int atile = 4 * (wave >> 1), btile = 4 * (wave & 1);

  for (int k0 = 0; k0 < 512; k0 += 32) {
    __syncthreads();
    g2l16(gA0 + k0, dA0);
    g2l16(gA1 + k0, dA1);
    g2l16(gB0 + k0, dB0);
    g2l16(gB1 + k0, dB1);
    __syncthreads();
    s16x8 af[4], bf[4];
#pragma unroll
    for (int mt = 0; mt < 4; ++mt)
      af[mt] = *(const s16x8*)&bA[(atile + mt) * 512 + lane * 8];
#pragma unroll
    for (int nt = 0; nt < 4; ++nt)
      bf[nt] = *(const s16x8*)&bB[(btile + nt) * 512 + lane * 8];
#pragma unroll
    for (int mt = 0; mt < 4; ++mt)
#pragma unroll
      for (int nt = 0; nt < 4; ++nt)
        acc[mt][nt] = __builtin_amdgcn_mfma_f32_16x16x32_bf16(
            af[mt], bf[nt], acc[mt][nt], 0, 0, 0);
  }
  // epilogue: C/D layout col=lane&15, row=(lane>>4)*4+reg
#pragma unroll
  for (int nt = 0; nt < 4; ++nt) {
    int col = n0 + wc + nt * 16 + fr;
    float bval = bias[col];
#pragma unroll
    for (int mt = 0; mt < 4; ++mt) {
      int rowb_l = wr + mt * 16 + hi2 * 4;
      if (mode == 1) {  // p packed, zero row u==1023
        int b = m0e >> 10, u0 = m0e & 1023;
        int h = col >> 6, cc = col & 63;
        size_t cbase = (size_t)(b * 8 + h) * 64 * 1024 + (cc >> 5) * 512 +
                       ((cc & 31) >> 3) * 128 + (cc & 7);
#pragma unroll
        for (int r = 0; r < 4; ++r) {
          int u = u0 + rowb_l + r;
          float val = (u >= 1023) ? 0.f : (acc[mt][nt][r] + bval);
          ((unsigned short*)O1)[cbase + (size_t)(u >> 4) * 1024 + (u & 15) * 8] =
              f2bf(val);
        }
      } else {  // mode 2: qc/qp packed (col<512), k packed (col>=512)
        int row = m0e + rowb_l;
        int b = row >> 9, s15 = row & 15, s16i = (row & 511) >> 4;
        if (col < 512) {
          int h = col >> 6, cc = col & 63;
          size_t idx = ((size_t)(b * 8 + h) * 32 + s16i) * 1024 +
                       (cc >> 5) * 512 + ((cc & 31) >> 3) * 128 + (cc & 7);
#pragma unroll
          for (int r = 0; r < 4; ++r) {
            float val = acc[mt][nt][r] + bval;
            ((unsigned short*)O1)[idx + (s15 + r) * 8] =
                f2bf((val + cbv[col]) * CSCALE);
            ((unsigned short*)O2)[idx + (s15 + r) * 8] =
                f2bf((val + pbv[col]) * CSCALE);
          }
        } else {
          int c2 = col - 512, h = c2 >> 6, cc = c2 & 63;
          size_t idx = ((size_t)(b * 8 + h) * 32 + s16i) * 1024 +
                       (cc >> 5) * 512 + ((cc & 31) >> 3) * 128 + (cc & 7);
#pragma unroll
          for (int r = 0; r < 4; ++r)
            ((unsigned short*)O3)[idx + (s15 + r) * 8] =
                f2bf(acc[mt][nt][r] + bval);
        }
      }
    }
  }
}

// ---------------- 64x64 GEMM body, BK=32, pairs=3, frag-packed LDS ---------
// Ah@Bh + Ah@Bl + Al@Bh. Wave w owns A rows [w*16,w*16+16) x all 64 cols.
// LDS: sAh/sAl/sBh/sBl each 4 x 1KB fragment tiles. Wave w stages its own
// Ah/Al tile and B tiles index w.  12 MFMA / iter / wave.
// mode 0: fp32 O1[row*512+col];  mode 3: vT packed trunc-split.
__device__ __forceinline__ void gemm64_body(
    unsigned short* sm, int mode, int m0, int n0,
    const unsigned short* __restrict__ Ah, const unsigned short* __restrict__ Al,
    const unsigned short* __restrict__ Bh, const unsigned short* __restrict__ Bl,
    const float* __restrict__ bias, void* __restrict__ O1,
    void* __restrict__ O2) {
  unsigned short* sAh = sm;
  unsigned short* sAl = sm + 2048;
  unsigned short* sBh = sm + 4096;
  unsigned short* sBl = sm + 6144;
  const int tid = threadIdx.x, lane = tid & 63, wave = tid >> 6;
  const int fr = lane & 15, hi2 = lane >> 4;
  const int l15 = lane & 15, lq = lane >> 4;

  f32x4 fz = {0.f, 0.f, 0.f, 0.f};
  f32x4 acc[4] = {fz, fz, fz, fz};

  const size_t arow = (size_t)(m0 + wave * 16 + l15) * 512 + lq * 8;
  const size_t brow = (size_t)(n0 + wave * 16 + l15) * 512 + lq * 8;
  const unsigned short* gAh = Ah + arow;
  const unsigned short* gAl = Al + arow;
  const unsigned short* gBh = Bh + brow;
  const unsigned short* gBl = Bl + brow;
  char* dAh = (char*)sAh + wave * 1024;
  char* dAl = (char*)sAl + wave * 1024;
  char* dBh = (char*)sBh + wave * 1024;
  char* dBl = (char*)sBl + wave * 1024;

  for (int k0 = 0; k0 < 512; k0 += 32) {
    __syncthreads();
    g2l16(gAh + k0, dAh);
    g2l16(gAl + k0, dAl);
    g2l16(gBh + k0, dBh);
    g2l16(gBl + k0, dBl);
    __syncthreads();
    s16x8 afh = *(const s16x8*)&sAh[wave * 512 + lane * 8];
    s16x8 afl = *(const s16x8*)&sAl[wave * 512 + lane * 8];
    s16x8 bfh[4], bfl[4];
#pragma unroll
    for (int nt = 0; nt < 4; ++nt) {
      bfh[nt] = *(const s16x8*)&sBh[nt * 512 + lane * 8];
      bfl[nt] = *(const s16x8*)&sBl[nt * 512 + lane * 8];
    }
#pragma unroll
    for (int nt = 0; nt < 4; ++nt) {
      acc[nt] = __builtin_amdgcn_mfma_f32_16x16x32_bf16(afh, bfh[nt], acc[nt], 0, 0, 0);
      acc[nt] = __builtin_amdgcn_mfma_f32_16x16x32_bf16(afh, bfl[nt], acc[nt], 0, 0, 0);
      acc[nt] = __builtin_amdgcn_mfma_f32_16x16x32_bf16(afl, bfh[nt], acc[nt], 0, 0, 0);
    }
  }
  // epilogue: wave's C tile = 16 rows x 64 cols
#pragma unroll
  for (int nt = 0; nt < 4; ++nt) {
    int col = n0 + nt * 16 + fr;
    float bval = bias[col];
    int rowb = m0 + wave * 16 + hi2 * 4;
    if (mode == 0) {
#pragma unroll
      for (int r = 0; r < 4; ++r)
        ((float*)O1)[(size_t)(rowb + r) * 512 + col] = acc[nt][r] + bval;
    } else {  // mode 3: vT packed (rows are t, col = h*64+d, n0 % 64 == 0)
      int b = rowb >> 9, t = rowb & 511;
      int h = col >> 6, d = col & 63;
      size_t idx = ((size_t)((b * 8 + h) * 4 + (d >> 4)) * 16 + (t >> 5)) * 512 +
                   ((t & 31) >> 3) * 128 + (d & 15) * 8 + (t & 7);
      u16x4 hv, lv;
#pragma unroll
      for (int r = 0; r < 4; ++r) {
        float val = acc[nt][r] + bval;
        unsigned short hh = bftr(val);
        hv[r] = hh;
        lv[r] = bftr(val - bf2f(hh));
      }
      *(u16x4*)((unsigned short*)O1 + idx) = hv;
      *(u16x4*)((unsigned short*)O2 + idx) = lv;
    }
  }
}

// merged projections: [0,1024) v 64x64 (heavy, first); [1024,1536) qk;
// [1536,2048) p.  16 KB static LDS everywhere.
__global__ __launch_bounds__(256) void proj_all(
    const unsigned short* __restrict__ xn_hi, const unsigned short* __restrict__ xn_lo,
    const unsigned short* __restrict__ pe_hi, const unsigned short* __restrict__ wqk,
    const unsigned short* __restrict__ wpm, const unsigned short* __restrict__ wvh,
    const unsigned short* __restrict__ wvl, const float* __restrict__ bqk,
    const float* __restrict__ bp, const float* __restrict__ bv,
    const float* __restrict__ cbv, const float* __restrict__ pbv,
    unsigned short* __restrict__ qc, unsigned short* __restrict__ qp,
    unsigned short* __restrict__ kb, unsigned short* __restrict__ pbuf,
    unsigned short* __restrict__ vth, unsigned short* __restrict__ vtl) {
  __shared__ __align__(16) unsigned short sm[8192];
  const int id = blockIdx.x;
  if (id < 1024) {  // v: M=8192, N=512, 64x64 tiles
    int m0 = (id >> 3) * 64, n0 = (id & 7) * 64;
    gemm64_body(sm, 3, m0, n0, xn_hi, xn_lo, wvh, wvl, bv, vth, vtl);
  } else if (id < 1536) {  // qk: M=8192, N=1024, 128x128 tiles
    int l = id - 1024;
    int m0 = (l >> 3) * 128, n0 = (l & 7) * 128;
    gemm128_body(sm, 2, m0, m0, n0, xn_hi, wqk, bqk, qc, qp, kb, cbv, pbv);
  } else {  // p: per-b 1023-row A, 128x128 tiles
    int l = id - 1536;
    int y = l >> 2, n0 = (l & 3) * 128;
    int b = y >> 3, mt8 = y & 7;
    gemm128_body(sm, 1, b * 1023 + mt8 * 128, b * 1024 + mt8 * 128, n0, pe_hi,
                 wpm, bp, pbuf, nullptr, nullptr, nullptr, nullptr);
  }
}

__global__ __launch_bounds__(256) void out_gemm(
    const unsigned short* __restrict__ ch, const unsigned short* __restrict__ cl,
    const unsigned short* __restrict__ woh, const unsigned short* __restrict__ wol,
    const float* __restrict__ bo, float* __restrict__ out) {
  __shared__ __align__(16) unsigned short sm[8192];
  const int id = blockIdx.x;  // 1024 blocks: 128 m x 8 n
  int m0 = (id >> 3) * 64, n0 = (id & 7) * 64;
  gemm64_body(sm, 0, m0, n0, ch, cl, woh, wol, bo, out, nullptr);
}

// ---------------- barrier-free flash attention, packed fragments -----------
__global__ __launch_bounds__(256) void flash_attn(
    const unsigned short* __restrict__ qc, const unsigned short* __restrict__ qp,
    const unsigned short* __restrict__ kb, const unsigned short* __restrict__ pm,
    const unsigned short* __restrict__ vth, const unsigned short* __restrict__ vtl,
    unsigned short* __restrict__ ctx_hi, unsigned short* __restrict__ ctx_lo,
    float* __restrict__ Op0, float* __restrict__ Op1, float* __restrict__ ml,
    int nsplit) {
  const int id = blockIdx.x;
  const int bh = id & 127, b = bh >> 3, h = bh & 7;
  const int rest = id >> 7, s_blk = rest & 7, half = rest >> 3;
  const int tid = threadIdx.x, wave = tid >> 6, lane = tid & 63;
  const int fr = lane & 15, hi2 = lane >> 4, fc = hi2 * 8;
  const int s0w = s_blk * 64 + wave * 16;
  const int crow = hi2 * 4;

  __shared__ __align__(16) unsigned short Ph_s[4][16][40];
  __shared__ __align__(16) unsigned short Pl_s[4][16][40];
  unsigned short(*Phw)[40] = Ph_s[wave];
  unsigned short(*Plw)[40] = Pl_s[wave];

  int srcl[4];
#pragma unroll
  for (int r = 0; r < 4; ++r) srcl[r] = (hi2 << 4) | ((fr - (crow + r) - 1) & 15);

  const size_t qtb = ((size_t)(b * 8 + h) * 32 + (s0w >> 4)) * 1024 + lane * 8;
  s16x8 aqc0 = *(const s16x8*)(qc + qtb);
  s16x8 aqc1 = *(const s16x8*)(qc + qtb + 512);
  s16x8 aqp0 = *(const s16x8*)(qp + qtb);
  s16x8 aqp1 = *(const s16x8*)(qp + qtb + 512);

  const unsigned short* kpk = kb + (size_t)(b * 8 + h) * 32 * 1024 + lane * 8;
  const unsigned short* ppk = pm + (size_t)(b * 8 + h) * 64 * 1024 + lane * 8;
  const unsigned short* vhk = vth + (size_t)(b * 8 + h) * 64 * 512 + lane * 8;
  const unsigned short* vlk = vtl + (size_t)(b * 8 + h) * 64 * 512 + lane * 8;

  f32x4 fz = {0.f, 0.f, 0.f, 0.f};
  f32x4 Oacc[4] = {fz, fz, fz, fz};
  float lsum[4] = {0.f, 0.f, 0.f, 0.f};

  const int nsteps = 16 / nsplit;
  const int step_lo = half * nsteps;
  for (int step = step_lo; step < step_lo + nsteps; ++step) {
    const int t0 = step * 32;
    const int u0w = t0 - s0w + 496;
    const int kt = t0 >> 4, ut = u0w >> 4, vt = t0 >> 5;
    f32x4 sc[2] = {fz, fz};
#pragma unroll
    for (int nt = 0; nt < 2; ++nt) {
      const unsigned short* kr = kpk + (size_t)(kt + nt) * 1024;
      s16x8 b0 = *(const s16x8*)kr;
      s16x8 b1 = *(const s16x8*)(kr + 512);
      sc[nt] = __builtin_amdgcn_mfma_f32_16x16x32_bf16(aqc0, b0, sc[nt], 0, 0, 0);
      sc[nt] = __builtin_amdgcn_mfma_f32_16x16x32_bf16(aqc1, b1, sc[nt], 0, 0, 0);
    }
    f32x4 sp[3];
#pragma unroll
    for (int nt = 0; nt < 3; ++nt) {
      const unsigned short* pr = ppk + (size_t)(ut + nt) * 1024;
      s16x8 b0 = *(const s16x8*)pr;
      s16x8 b1 = *(const s16x8*)(pr + 512);
      f32x4 t = fz;
      t = __builtin_amdgcn_mfma_f32_16x16x32_bf16(aqp0, b0, t, 0, 0, 0);
      t = __builtin_amdgcn_mfma_f32_16x16x32_bf16(aqp1, b1, t, 0, 0, 0);
      sp[nt] = t;
    }
    float sj[3][4];
#pragma unroll
    for (int j = 0; j < 3; ++j)
#pragma unroll
      for (int r = 0; r < 4; ++r) sj[j][r] = __shfl(sp[j][r], srcl[r], 64);
#pragma unroll
    for (int nt = 0; nt < 2; ++nt) {
      int tc = nt * 16 + fr;
#pragma unroll
      for (int r = 0; r < 4; ++r) {
        float pos = (fr <= crow + r) ? sj[nt][r] : sj[nt + 1][r];
        float e = EXP2(sc[nt][r] + pos);
        lsum[r] += e;
        unsigned short hh = bftr(e);
        Phw[crow + r][tc] = hh;
        Plw[crow + r][tc] = bftr(e - bf2f(hh));
      }
    }
    s16x8 ah = *(const s16x8*)&Phw[fr][fc];
    s16x8 alo = *(const s16x8*)&Plw[fr][fc];
#pragma unroll
    for (int nt = 0; nt < 4; ++nt) {
      const unsigned short* vr = vhk + (size_t)(nt * 16 + vt) * 512;
      const unsigned short* vr2 = vlk + (size_t)(nt * 16 + vt) * 512;
      s16x8 bh = *(const s16x8*)vr;
      s16x8 bl = *(const s16x8*)vr2;
      Oacc[nt] = __builtin_amdgcn_mfma_f32_16x16x32_bf16(ah, bh, Oacc[nt], 0, 0, 0);
      Oacc[nt] = __builtin_amdgcn_mfma_f32_16x16x32_bf16(ah, bl, Oacc[nt], 0, 0, 0);
      Oacc[nt] = __builtin_amdgcn_mfma_f32_16x16x32_bf16(alo, bh, Oacc[nt], 0, 0, 0);
    }
  }
#pragma unroll
  for (int d = 1; d < 16; d <<= 1)
#pragma unroll
    for (int r = 0; r < 4; ++r) lsum[r] += __shfl_xor(lsum[r], d, 64);
  if (nsplit == 1) {
#pragma unroll
    for (int nt = 0; nt < 4; ++nt)
#pragma unroll
      for (int r = 0; r < 4; ++r) {
        float o = Oacc[nt][r] / lsum[r];
        size_t idx =
            (size_t)(b * 512 + s0w + crow + r) * 512 + h * 64 + nt * 16 + fr;
        unsigned short hh = bftr(o);
        ctx_hi[idx] = hh;
        ctx_lo[idx] = bftr(o - bf2f(hh));
      }
  } else {
    float* op = half ? Op1 : Op0;
#pragma unroll
    for (int nt = 0; nt < 4; ++nt)
#pragma unroll
      for (int r = 0; r < 4; ++r)
        op[(size_t)(b * 512 + s0w + crow + r) * 512 + h * 64 + nt * 16 + fr] =
            Oacc[nt][r];
    if ((lane & 15) == 0) {
#pragma unroll
      for (int r = 0; r < 4; ++r)
        ml[(size_t)half * 65536 + (size_t)(b * 512 + s0w + crow + r) * 8 + h] =
            lsum[r];
    }
  }
}

// ---------------- merge the two t-halves ----------------------------------
__global__ __launch_bounds__(256) void merge_halves(
    const float* __restrict__ Op0, const float* __restrict__ Op1,
    const float* __restrict__ ml, unsigned short* __restrict__ ch,
    unsigned short* __restrict__ cl) {
  int e0 = (blockIdx.x * 256 + threadIdx.x) * 4;
  int r = e0 >> 9, c = e0 & 511, h = c >> 6;
  float inv = 1.0f / (ml[(size_t)r * 8 + h] + ml[65536 + (size_t)r * 8 + h]);
  f32x4 o1 = *(const f32x4*)(Op0 + e0);
  f32x4 o2 = *(const f32x4*)(Op1 + e0);
  u16x4 hv, lv;
#pragma unroll
  for (int j = 0; j < 4; ++j) {
    float o = (o1[j] + o2[j]) * inv;
    unsigned short hh = bftr(o);
    hv[j] = hh;
    lv[j] = bftr(o - bf2f(hh));
  }
  *(u16x4*)(ch + e0) = hv;
  *(u16x4*)(cl + e0) = lv;
}

// ---------------------------------------------------------------------------
extern "C" void kernel_launch(void* const* d_in, const int* in_sizes, int n_in,
                              void* d_out, int out_size, void* d_ws,
                              size_t ws_size, hipStream_t stream) {
  const float* x = (const float*)d_in[0];
  const float* pe = (const float*)d_in[1];
  const float* ln_g = (const float*)d_in[2];
  const float* ln_b = (const float*)d_in[3];
  const float* Wq = (const float*)d_in[4];
  const float* bq = (const float*)d_in[5];
  const float* Wk = (const float*)d_in[6];
  const float* bk = (const float*)d_in[7];
  const float* Wv = (const float*)d_in[8];
  const float* bv = (const float*)d_in[9];
  const float* Wp = (const float*)d_in[10];
  const float* bp = (const float*)d_in[11];
  const float* cb = (const float*)d_in[12];
  const float* pb = (const float*)d_in[13];
  const float* Wo = (const float*)d_in[14];
  const float* bo = (const float*)d_in[15];
  float* out = (float*)d_out;

  char* ws = (char*)d_ws;
  size_t off = 0;
  auto alloc = [&](size_t bytes) -> char* {
    char* ptr = ws + off;
    off = (off + bytes + 255) & ~(size_t)255;
    return ptr;
  };
  // region A: xn hi/lo -> later Opart half 0 (fp32, same byte count)
  char* regA = alloc((size_t)2 * 8192 * 512 * 2);
  unsigned short* xn_hi = (unsigned short*)regA;
  unsigned short* xn_lo = (unsigned short*)(regA + (size_t)8192 * 512 * 2);
  float* Op0 = (float*)regA;
  // region B: pe_hi -> later Opart half 1
  char* regB = alloc((size_t)16384 * 512 * 2);
  unsigned short* pe_hi = (unsigned short*)regB;
  float* Op1 = (float*)regB;
  unsigned short* vt_hi = (unsigned short*)alloc((size_t)8192 * 512 * 2);
  unsigned short* vt_lo = (unsigned short*)alloc((size_t)8192 * 512 * 2);
  unsigned short* wqk_hi = (unsigned short*)alloc((size_t)1024 * 512 * 2);
  unsigned short* wp_hi = (unsigned short*)alloc((size_t)512 * 512 * 2);
  unsigned short* wv_hi = (unsigned short*)alloc((size_t)512 * 512 * 2);
  unsigned short* wv_lo = (unsigned short*)alloc((size_t)512 * 512 * 2);
  unsigned short* wo_hi = (unsigned short*)alloc((size_t)512 * 512 * 2);
  unsigned short* wo_lo = (unsigned short*)alloc((size_t)512 * 512 * 2);
  float* bqk = (float*)alloc(1024 * 4);
  unsigned short* qc = (unsigned short*)alloc((size_t)8192 * 512 * 2);
  unsigned short* qp = (unsigned short*)alloc((size_t)8192 * 512 * 2);
  unsigned short* kbuf = (unsigned short*)alloc((size_t)8192 * 512 * 2);
  unsigned short* pbuf = (unsigned short*)alloc((size_t)16384 * 512 * 2);
  float* mlbuf = (float*)alloc((size_t)2 * 8192 * 8 * 4);

  int nsplit = 2;
  if (ws_size < off) {
    fprintf(stderr, "kernel_launch: ws too small (need %zu, have %zu)\n", off,
            ws_size);
    return;
  }
  unsigned short* ctx_hi = (nsplit == 2) ? qc : xn_hi;
  unsigned short* ctx_lo = (nsplit == 2) ? qp : xn_lo;

  megaprep<<<17664, 256, 0, stream>>>(x, ln_g, ln_b, xn_hi, xn_lo, pe, pe_hi,
                                      Wq, Wk, Wp, Wv, Wo, bq, bk, wqk_hi,
                                      wp_hi, wv_hi, wv_lo, wo_hi, wo_lo, bqk);
  proj_all<<<2048, 256, 0, stream>>>(xn_hi, xn_lo, pe_hi, wqk_hi, wp_hi,
                                     wv_hi, wv_lo, bqk, bp, bv, cb, pb, qc,
                                     qp, kbuf, pbuf, vt_hi, vt_lo);
  flash_attn<<<1024 * nsplit, 256, 0, stream>>>(qc, qp, kbuf, pbuf, vt_hi,
                                                vt_lo, ctx_hi, ctx_lo, Op0,
                                                Op1, mlbuf, nsplit);
  if (nsplit == 2)
    merge_halves<<<4096, 256, 0, stream>>>(Op0, Op1, mlbuf, ctx_hi, ctx_lo);
  out_gemm<<<1024, 256, 0, stream>>>(ctx_hi, ctx_lo, wo_hi, wo_lo, bo, out);
}

// Round 7
// 279.677 us; speedup vs baseline: 1.0680x; 1.0680x over previous
//
#include <hip/hip_runtime.h>
#include <cstdio>
#include <cstdint>

// ---------------------------------------------------------------------------
// Transformer-XL relative MHA, MI355X/gfx950.  B=16 T=512 D=512 H=8 hd=64.
// Round 7: R6's conflict-free fragment-order LDS staging kept, but fat tiles
// restored: v and out use 64x128 pairs-3 tiles (512 blocks each, 24 MFMA per
// iter per wave, A re-read 4x not 8x); qk/p 128x128. R6's 64x64 tiles were
// L2/barrier-bound (12 MFMA per 16KB staged) -> 100us proj; this fixes that.
// Flash unchanged (packed fragments, barrier-free, fixed-max softmax).
// Precision: logit path bf16 (softmax attenuates); v/PV/out split-bf16.
// ---------------------------------------------------------------------------

typedef short s16x8 __attribute__((ext_vector_type(8)));
typedef float f32x4 __attribute__((ext_vector_type(4)));
typedef unsigned short u16x4 __attribute__((ext_vector_type(4)));

#define CSCALE 0.1803368801111204f  // log2(e)/8

#if __has_builtin(__builtin_amdgcn_exp2f)
#define EXP2(x) __builtin_amdgcn_exp2f(x)
#else
#define EXP2(x) exp2f(x)
#endif

__device__ __forceinline__ unsigned short f2bf(float f) {  // RNE
  unsigned int u = __builtin_bit_cast(unsigned int, f);
  unsigned int r = (u + 0x7FFFu + ((u >> 16) & 1u)) >> 16;
  return (unsigned short)r;
}
__device__ __forceinline__ unsigned short bftr(float f) {  // truncate
  return (unsigned short)(__builtin_bit_cast(unsigned int, f) >> 16);
}
__device__ __forceinline__ float bf2f(unsigned short h) {
  unsigned int u = ((unsigned int)h) << 16;
  return __builtin_bit_cast(float, u);
}

// async global->LDS, 16B/lane; LDS dest = wave-uniform base + lane*16
__device__ __forceinline__ void g2l16(const void* g, void* l) {
  __builtin_amdgcn_global_load_lds(
      (const __attribute__((address_space(1))) void*)g,
      (__attribute__((address_space(3))) void*)l, 16, 0, 0);
}

// ---------------- fused prep: ln + pe cast + weight casts ------------------
__global__ __launch_bounds__(256) void megaprep(
    const float* __restrict__ x, const float* __restrict__ g,
    const float* __restrict__ bb, unsigned short* __restrict__ xh,
    unsigned short* __restrict__ xl, const float* __restrict__ pe,
    unsigned short* __restrict__ ped, const float* __restrict__ Wq,
    const float* __restrict__ Wk, const float* __restrict__ Wp,
    const float* __restrict__ Wv, const float* __restrict__ Wo,
    const float* __restrict__ bq, const float* __restrict__ bk,
    unsigned short* __restrict__ wqk, unsigned short* __restrict__ wpm,
    unsigned short* __restrict__ wvh, unsigned short* __restrict__ wvl,
    unsigned short* __restrict__ woh, unsigned short* __restrict__ wol,
    float* __restrict__ bqk) {
  __shared__ float red[8];
  const int bid = blockIdx.x, tid = threadIdx.x;
  if (bid < 8192) {  // LayerNorm, one row/block
    const int wave = tid >> 6, lane = tid & 63;
    const float* xr = x + (size_t)bid * 512;
    float v0 = xr[tid], v1 = xr[tid + 256];
    float s = v0 + v1, ss = v0 * v0 + v1 * v1;
#pragma unroll
    for (int d = 1; d < 64; d <<= 1) {
      s += __shfl_xor(s, d, 64);
      ss += __shfl_xor(ss, d, 64);
    }
    if (lane == 0) { red[wave] = s; red[4 + wave] = ss; }
    __syncthreads();
    s = red[0] + red[1] + red[2] + red[3];
    ss = red[4] + red[5] + red[6] + red[7];
    const float mu = s * (1.0f / 512.0f);
    const float var = ss * (1.0f / 512.0f) - mu * mu;
    const float rstd = rsqrtf(var + 1e-5f);
#pragma unroll
    for (int i = 0; i < 2; i++) {
      int d = tid + i * 256;
      float v = (i == 0) ? v0 : v1;
      float xn = (v - mu) * rstd * g[d] + bb[d];
      unsigned short hi = f2bf(xn);
      xh[(size_t)bid * 512 + d] = hi;
      xl[(size_t)bid * 512 + d] = f2bf(xn - bf2f(hi));
    }
  } else if (bid < 16384) {  // pe cast x4 (pad rows -> 0)
    int e0 = (bid - 8192) * 1024 + tid * 4;
    u16x4 o = {0, 0, 0, 0};
    if (e0 < 16368 * 512) {
      float4 v = *(const float4*)(pe + e0);
      o[0] = f2bf(v.x); o[1] = f2bf(v.y); o[2] = f2bf(v.z); o[3] = f2bf(v.w);
    }
    *(u16x4*)(ped + e0) = o;
  } else {  // weights x4
    int idx = (bid - 16384) * 1024 + tid * 4;
    int region = idx >> 18, off = idx & 262143;
    const float* src = (region == 0)   ? Wq
                       : (region == 1) ? Wk
                       : (region == 2) ? Wp
                       : (region == 3) ? Wv
                                       : Wo;
    float4 w = *(const float4*)(src + off);
    float wv4[4] = {w.x, w.y, w.z, w.w};
    u16x4 hv, lv;
#pragma unroll
    for (int j = 0; j < 4; j++) {
      unsigned short h = f2bf(wv4[j]);
      hv[j] = h;
      lv[j] = f2bf(wv4[j] - bf2f(h));
    }
    if (region == 0) {
      *(u16x4*)(wqk + off) = hv;
    } else if (region == 1) {
      *(u16x4*)(wqk + 262144 + off) = hv;
    } else if (region == 2) {
      *(u16x4*)(wpm + off) = hv;
    } else if (region == 3) {
      *(u16x4*)(wvh + off) = hv;
      *(u16x4*)(wvl + off) = lv;
    } else {
      *(u16x4*)(woh + off) = hv;
      *(u16x4*)(wol + off) = lv;
    }
    if (idx < 1024) {
#pragma unroll
      for (int j = 0; j < 4; j++) {
        int ii = idx + j;
        bqk[ii] = (ii < 512) ? bq[ii] : bk[ii - 512];
      }
    }
  }
}

// ---------------- 128x128 GEMM body, BK=32, pairs=1, frag-packed LDS -------
// mode 1: p packed epilogue;  mode 2: qc/qp/k packed epilogue.
__device__ __forceinline__ void gemm128_body(
    unsigned short* sm, int mode, int arow0, int m0e, int n0,
    const unsigned short* __restrict__ A, const unsigned short* __restrict__ B,
    const float* __restrict__ bias, void* __restrict__ O1, void* __restrict__ O2,
    void* __restrict__ O3, const float* __restrict__ cbv,
    const float* __restrict__ pbv) {
  unsigned short* bA = sm;          // 4096 shorts
  unsigned short* bB = sm + 4096;   // 4096 shorts
  const int tid = threadIdx.x, lane = tid & 63, wave = tid >> 6;
  const int wr = (wave >> 1) * 64, wc = (wave & 1) * 64;
  const int fr = lane & 15, hi2 = lane >> 4;
  const int l15 = lane & 15, lq = lane >> 4;

  f32x4 fz = {0.f, 0.f, 0.f, 0.f};
  f32x4 acc[4][4];
#pragma unroll
  for (int i = 0; i < 4; i++)
#pragma unroll
    for (int j = 0; j < 4; j++) acc[i][j] = fz;

  const unsigned short* gA0 = A + (size_t)(arow0 + wave * 32 + l15) * 512 + lq * 8;
  const unsigned short* gA1 = gA0 + 16 * 512;
  const unsigned short* gB0 = B + (size_t)(n0 + wave * 32 + l15) * 512 + lq * 8;
  const unsigned short* gB1 = gB0 + 16 * 512;
  char* dA0 = (char*)bA + wave * 2048;
  char* dA1 = dA0 + 1024;
  char* dB0 = (char*)bB + wave * 2048;
  char* dB1 = dB0 + 1024;
  const int atile = 4 * (wave >> 1), btile = 4 * (wave & 1);

  for (int k0 = 0; k0 < 512; k0 += 32) {
    __syncthreads();
    g2l16(gA0 + k0, dA0);
    g2l16(gA1 + k0, dA1);
    g2l16(gB0 + k0, dB0);
    g2l16(gB1 + k0, dB1);
    __syncthreads();
    s16x8 af[4], bf[4];
#pragma unroll
    for (int mt = 0; mt < 4; ++mt)
      af[mt] = *(const s16x8*)&bA[(atile + mt) * 512 + lane * 8];
#pragma unroll
    for (int nt = 0; nt < 4; ++nt)
      bf[nt] = *(const s16x8*)&bB[(btile + nt) * 512 + lane * 8];
#pragma unroll
    for (int mt = 0; mt < 4; ++mt)
#pragma unroll
      for (int nt = 0; nt < 4; ++nt)
        acc[mt][nt] = __builtin_amdgcn_mfma_f32_16x16x32_bf16(
            af[mt], bf[nt], acc[mt][nt], 0, 0, 0);
  }
  // epilogue: C/D layout col=lane&15, row=(lane>>4)*4+reg
#pragma unroll
  for (int nt = 0; nt < 4; ++nt) {
    int col = n0 + wc + nt * 16 + fr;
    float bval = bias[col];
#pragma unroll
    for (int mt = 0; mt < 4; ++mt) {
      int rowb_l = wr + mt * 16 + hi2 * 4;
      if (mode == 1) {  // p packed, zero row u==1023
        int b = m0e >> 10, u0 = m0e & 1023;
        int h = col >> 6, cc = col & 63;
        size_t cbase = (size_t)(b * 8 + h) * 64 * 1024 + (cc >> 5) * 512 +
                       ((cc & 31) >> 3) * 128 + (cc & 7);
#pragma unroll
        for (int r = 0; r < 4; ++r) {
          int u = u0 + rowb_l + r;
          float val = (u >= 1023) ? 0.f : (acc[mt][nt][r] + bval);
          ((unsigned short*)O1)[cbase + (size_t)(u >> 4) * 1024 + (u & 15) * 8] =
              f2bf(val);
        }
      } else {  // mode 2: qc/qp packed (col<512), k packed (col>=512)
        int row = m0e + rowb_l;
        int b = row >> 9, s15 = row & 15, s16i = (row & 511) >> 4;
        if (col < 512) {
          int h = col >> 6, cc = col & 63;
          size_t idx = ((size_t)(b * 8 + h) * 32 + s16i) * 1024 +
                       (cc >> 5) * 512 + ((cc & 31) >> 3) * 128 + (cc & 7);
#pragma unroll
          for (int r = 0; r < 4; ++r) {
            float val = acc[mt][nt][r] + bval;
            ((unsigned short*)O1)[idx + (s15 + r) * 8] =
                f2bf((val + cbv[col]) * CSCALE);
            ((unsigned short*)O2)[idx + (s15 + r) * 8] =
                f2bf((val + pbv[col]) * CSCALE);
          }
        } else {
          int c2 = col - 512, h = c2 >> 6, cc = c2 & 63;
          size_t idx = ((size_t)(b * 8 + h) * 32 + s16i) * 1024 +
                       (cc >> 5) * 512 + ((cc & 31) >> 3) * 128 + (cc & 7);
#pragma unroll
          for (int r = 0; r < 4; ++r)
            ((unsigned short*)O3)[idx + (s15 + r) * 8] =
                f2bf(acc[mt][nt][r] + bval);
        }
      }
    }
  }
}

// ---------------- 64x128 GEMM body, BK=32, pairs=3, frag-packed LDS --------
// Ah@Bh + Ah@Bl + Al@Bh. 4 waves = 4 col strips of 32. Per k-chunk per wave:
// 6 g2l16 staged, 24 MFMA. LDS 24 KB. All ds_read_b128 = base + lane*16.
// mode 0: fp32 O1[row*512+col];  mode 3: vT packed trunc-split.
__device__ __forceinline__ void gemm64x128_body(
    unsigned short* sm, int mode, int m0, int n0,
    const unsigned short* __restrict__ Ah, const unsigned short* __restrict__ Al,
    const unsigned short* __restrict__ Bh, const unsigned short* __restrict__ Bl,
    const float* __restrict__ bias, void* __restrict__ O1,
    void* __restrict__ O2) {
  unsigned short* sAh = sm;            // 2048 shorts (4 tiles)
  unsigned short* sAl = sm + 2048;     // 2048
  unsigned short* sBh = sm + 4096;     // 4096 (8 tiles)
  unsigned short* sBl = sm + 8192;     // 4096
  const int tid = threadIdx.x, lane = tid & 63, wave = tid >> 6;
  const int fr = lane & 15, hi2 = lane >> 4;
  const int l15 = lane & 15, lq = lane >> 4;

  f32x4 fz = {0.f, 0.f, 0.f, 0.f};
  f32x4 acc[4][2] = {{fz, fz}, {fz, fz}, {fz, fz}, {fz, fz}};

  const size_t aoff = (size_t)(m0 + wave * 16 + l15) * 512 + lq * 8;
  const size_t boff = (size_t)(n0 + wave * 32 + l15) * 512 + lq * 8;
  const unsigned short* gAh = Ah + aoff;
  const unsigned short* gAl = Al + aoff;
  const unsigned short* gBh0 = Bh + boff;
  const unsigned short* gBh1 = gBh0 + 16 * 512;
  const unsigned short* gBl0 = Bl + boff;
  const unsigned short* gBl1 = gBl0 + 16 * 512;
  char* dAh = (char*)sAh + wave * 1024;
  char* dAl = (char*)sAl + wave * 1024;
  char* dBh0 = (char*)sBh + wave * 2048;
  char* dBh1 = dBh0 + 1024;
  char* dBl0 = (char*)sBl + wave * 2048;
  char* dBl1 = dBl0 + 1024;

  for (int k0 = 0; k0 < 512; k0 += 32) {
    __syncthreads();
    g2l16(gAh + k0, dAh);
    g2l16(gAl + k0, dAl);
    g2l16(gBh0 + k0, dBh0);
    g2l16(gBh1 + k0, dBh1);
    g2l16(gBl0 + k0, dBl0);
    g2l16(gBl1 + k0, dBl1);
    __syncthreads();
    s16x8 afh[4], afl[4], bfh[2], bfl[2];
#pragma unroll
    for (int mt = 0; mt < 4; ++mt) {
      afh[mt] = *(const s16x8*)&sAh[mt * 512 + lane * 8];
      afl[mt] = *(const s16x8*)&sAl[mt * 512 + lane * 8];
    }
#pragma unroll
    for (int nt = 0; nt < 2; ++nt) {
      bfh[nt] = *(const s16x8*)&sBh[(2 * wave + nt) * 512 + lane * 8];
      bfl[nt] = *(const s16x8*)&sBl[(2 * wave + nt) * 512 + lane * 8];
    }
#pragma unroll
    for (int mt = 0; mt < 4; ++mt)
#pragma unroll
      for (int nt = 0; nt < 2; ++nt) {
        acc[mt][nt] = __builtin_amdgcn_mfma_f32_16x16x32_bf16(
            afh[mt], bfh[nt], acc[mt][nt], 0, 0, 0);
        acc[mt][nt] = __builtin_amdgcn_mfma_f32_16x16x32_bf16(
            afh[mt], bfl[nt], acc[mt][nt], 0, 0, 0);
        acc[mt][nt] = __builtin_amdgcn_mfma_f32_16x16x32_bf16(
            afl[mt], bfh[nt], acc[mt][nt], 0, 0, 0);
      }
  }
  // epilogue: wave's C strip = 64 rows x cols [n0+wave*32, +32)
#pragma unroll
  for (int nt = 0; nt < 2; ++nt) {
    int col = n0 + wave * 32 + nt * 16 + fr;
    float bval = bias[col];
#pragma unroll
    for (int mt = 0; mt < 4; ++mt) {
      int rowb = m0 + mt * 16 + hi2 * 4;
      if (mode == 0) {
#pragma unroll
        for (int r = 0; r < 4; ++r)
          ((float*)O1)[(size_t)(rowb + r) * 512 + col] = acc[mt][nt][r] + bval;
      } else {  // mode 3: vT packed (rows are t, col = h*64+d)
        int b = rowb >> 9, t = rowb & 511;
        int h = col >> 6, d = col & 63;
        size_t idx = ((size_t)((b * 8 + h) * 4 + (d >> 4)) * 16 + (t >> 5)) * 512 +
                     ((t & 31) >> 3) * 128 + (d & 15) * 8 + (t & 7);
        u16x4 hv, lv;
#pragma unroll
        for (int r = 0; r < 4; ++r) {
          float val = acc[mt][nt][r] + bval;
          unsigned short hh = bftr(val);
          hv[r] = hh;
          lv[r] = bftr(val - bf2f(hh));
        }
        *(u16x4*)((unsigned short*)O1 + idx) = hv;
        *(u16x4*)((unsigned short*)O2 + idx) = lv;
      }
    }
  }
}

// merged projections: [0,512) v 64x128 pairs-3; [512,1024) qk 128x128;
// [1024,1536) p 128x128.
__global__ __launch_bounds__(256) void proj_all(
    const unsigned short* __restrict__ xn_hi, const unsigned short* __restrict__ xn_lo,
    const unsigned short* __restrict__ pe_hi, const unsigned short* __restrict__ wqk,
    const unsigned short* __restrict__ wpm, const unsigned short* __restrict__ wvh,
    const unsigned short* __restrict__ wvl, const float* __restrict__ bqk,
    const float* __restrict__ bp, const float* __restrict__ bv,
    const float* __restrict__ cbv, const float* __restrict__ pbv,
    unsigned short* __restrict__ qc, unsigned short* __restrict__ qp,
    unsigned short* __restrict__ kb, unsigned short* __restrict__ pbuf,
    unsigned short* __restrict__ vth, unsigned short* __restrict__ vtl) {
  __shared__ __align__(16) unsigned short sm[12288];
  const int id = blockIdx.x;
  if (id < 512) {  // v: M=8192 (128 m-tiles of 64), N=512 (4 n-tiles of 128)
    int m0 = (id >> 2) * 64, n0 = (id & 3) * 128;
    gemm64x128_body(sm, 3, m0, n0, xn_hi, xn_lo, wvh, wvl, bv, vth, vtl);
  } else if (id < 1024) {  // qk: M=8192, N=1024, 128x128 tiles
    int l = id - 512;
    int m0 = (l >> 3) * 128, n0 = (l & 7) * 128;
    gemm128_body(sm, 2, m0, m0, n0, xn_hi, wqk, bqk, qc, qp, kb, cbv, pbv);
  } else {  // p: per-b 1023-row A, 128x128 tiles
    int l = id - 1024;
    int y = l >> 2, n0 = (l & 3) * 128;
    int b = y >> 3, mt8 = y & 7;
    gemm128_body(sm, 1, b * 1023 + mt8 * 128, b * 1024 + mt8 * 128, n0, pe_hi,
                 wpm, bp, pbuf, nullptr, nullptr, nullptr, nullptr);
  }
}

__global__ __launch_bounds__(256) void out_gemm(
    const unsigned short* __restrict__ ch, const unsigned short* __restrict__ cl,
    const unsigned short* __restrict__ woh, const unsigned short* __restrict__ wol,
    const float* __restrict__ bo, float* __restrict__ out) {
  __shared__ __align__(16) unsigned short sm[12288];
  const int id = blockIdx.x;  // 512 blocks: 128 m-tiles of 64 x 4 n-tiles of 128
  int m0 = (id >> 2) * 64, n0 = (id & 3) * 128;
  gemm64x128_body(sm, 0, m0, n0, ch, cl, woh, wol, bo, out, nullptr);
}

// ---------------- barrier-free flash attention, packed fragments -----------
__global__ __launch_bounds__(256) void flash_attn(
    const unsigned short* __restrict__ qc, const unsigned short* __restrict__ qp,
    const unsigned short* __restrict__ kb, const unsigned short* __restrict__ pm,
    const unsigned short* __restrict__ vth, const unsigned short* __restrict__ vtl,
    unsigned short* __restrict__ ctx_hi, unsigned short* __restrict__ ctx_lo,
    float* __restrict__ Op0, float* __restrict__ Op1, float* __restrict__ ml,
    int nsplit) {
  const int id = blockIdx.x;
  const int bh = id & 127, b = bh >> 3, h = bh & 7;
  const int rest = id >> 7, s_blk = rest & 7, half = rest >> 3;
  const int tid = threadIdx.x, wave = tid >> 6, lane = tid & 63;
  const int fr = lane & 15, hi2 = lane >> 4, fc = hi2 * 8;
  const int s0w = s_blk * 64 + wave * 16;
  const int crow = hi2 * 4;

  __shared__ __align__(16) unsigned short Ph_s[4][16][40];
  __shared__ __align__(16) unsigned short Pl_s[4][16][40];
  unsigned short(*Phw)[40] = Ph_s[wave];
  unsigned short(*Plw)[40] = Pl_s[wave];

  int srcl[4];
#pragma unroll
  for (int r = 0; r < 4; ++r) srcl[r] = (hi2 << 4) | ((fr - (crow + r) - 1) & 15);

  const size_t qtb = ((size_t)(b * 8 + h) * 32 + (s0w >> 4)) * 1024 + lane * 8;
  s16x8 aqc0 = *(const s16x8*)(qc + qtb);
  s16x8 aqc1 = *(const s16x8*)(qc + qtb + 512);
  s16x8 aqp0 = *(const s16x8*)(qp + qtb);
  s16x8 aqp1 = *(const s16x8*)(qp + qtb + 512);

  const unsigned short* kpk = kb + (size_t)(b * 8 + h) * 32 * 1024 + lane * 8;
  const unsigned short* ppk = pm + (size_t)(b * 8 + h) * 64 * 1024 + lane * 8;
  const unsigned short* vhk = vth + (size_t)(b * 8 + h) * 64 * 512 + lane * 8;
  const unsigned short* vlk = vtl + (size_t)(b * 8 + h) * 64 * 512 + lane * 8;

  f32x4 fz = {0.f, 0.f, 0.f, 0.f};
  f32x4 Oacc[4] = {fz, fz, fz, fz};
  float lsum[4] = {0.f, 0.f, 0.f, 0.f};

  const int nsteps = 16 / nsplit;
  const int step_lo = half * nsteps;
  for (int step = step_lo; step < step_lo + nsteps; ++step) {
    const int t0 = step * 32;
    const int u0w = t0 - s0w + 496;
    const int kt = t0 >> 4, ut = u0w >> 4, vt = t0 >> 5;
    f32x4 sc[2] = {fz, fz};
#pragma unroll
    for (int nt = 0; nt < 2; ++nt) {
      const unsigned short* kr = kpk + (size_t)(kt + nt) * 1024;
      s16x8 b0 = *(const s16x8*)kr;
      s16x8 b1 = *(const s16x8*)(kr + 512);
      sc[nt] = __builtin_amdgcn_mfma_f32_16x16x32_bf16(aqc0, b0, sc[nt], 0, 0, 0);
      sc[nt] = __builtin_amdgcn_mfma_f32_16x16x32_bf16(aqc1, b1, sc[nt], 0, 0, 0);
    }
    f32x4 sp[3];
#pragma unroll
    for (int nt = 0; nt < 3; ++nt) {
      const unsigned short* pr = ppk + (size_t)(ut + nt) * 1024;
      s16x8 b0 = *(const s16x8*)pr;
      s16x8 b1 = *(const s16x8*)(pr + 512);
      f32x4 t = fz;
      t = __builtin_amdgcn_mfma_f32_16x16x32_bf16(aqp0, b0, t, 0, 0, 0);
      t = __builtin_amdgcn_mfma_f32_16x16x32_bf16(aqp1, b1, t, 0, 0, 0);
      sp[nt] = t;
    }
    float sj[3][4];
#pragma unroll
    for (int j = 0; j < 3; ++j)
#pragma unroll
      for (int r = 0; r < 4; ++r) sj[j][r] = __shfl(sp[j][r], srcl[r], 64);
#pragma unroll
    for (int nt = 0; nt < 2; ++nt) {
      int tc = nt * 16 + fr;
#pragma unroll
      for (int r = 0; r < 4; ++r) {
        float pos = (fr <= crow + r) ? sj[nt][r] : sj[nt + 1][r];
        float e = EXP2(sc[nt][r] + pos);
        lsum[r] += e;
        unsigned short hh = bftr(e);
        Phw[crow + r][tc] = hh;
        Plw[crow + r][tc] = bftr(e - bf2f(hh));
      }
    }
    s16x8 ah = *(const s16x8*)&Phw[fr][fc];
    s16x8 alo = *(const s16x8*)&Plw[fr][fc];
#pragma unroll
    for (int nt = 0; nt < 4; ++nt) {
      const unsigned short* vr = vhk + (size_t)(nt * 16 + vt) * 512;
      const unsigned short* vr2 = vlk + (size_t)(nt * 16 + vt) * 512;
      s16x8 bh = *(const s16x8*)vr;
      s16x8 bl = *(const s16x8*)vr2;
      Oacc[nt] = __builtin_amdgcn_mfma_f32_16x16x32_bf16(ah, bh, Oacc[nt], 0, 0, 0);
      Oacc[nt] = __builtin_amdgcn_mfma_f32_16x16x32_bf16(ah, bl, Oacc[nt], 0, 0, 0);
      Oacc[nt] = __builtin_amdgcn_mfma_f32_16x16x32_bf16(alo, bh, Oacc[nt], 0, 0, 0);
    }
  }
#pragma unroll
  for (int d = 1; d < 16; d <<= 1)
#pragma unroll
    for (int r = 0; r < 4; ++r) lsum[r] += __shfl_xor(lsum[r], d, 64);
  if (nsplit == 1) {
#pragma unroll
    for (int nt = 0; nt < 4; ++nt)
#pragma unroll
      for (int r = 0; r < 4; ++r) {
        float o = Oacc[nt][r] / lsum[r];
        size_t idx =
            (size_t)(b * 512 + s0w + crow + r) * 512 + h * 64 + nt * 16 + fr;
        unsigned short hh = bftr(o);
        ctx_hi[idx] = hh;
        ctx_lo[idx] = bftr(o - bf2f(hh));
      }
  } else {
    float* op = half ? Op1 : Op0;
#pragma unroll
    for (int nt = 0; nt < 4; ++nt)
#pragma unroll
      for (int r = 0; r < 4; ++r)
        op[(size_t)(b * 512 + s0w + crow + r) * 512 + h * 64 + nt * 16 + fr] =
            Oacc[nt][r];
    if ((lane & 15) == 0) {
#pragma unroll
      for (int r = 0; r < 4; ++r)
        ml[(size_t)half * 65536 + (size_t)(b * 512 + s0w + crow + r) * 8 + h] =
            lsum[r];
    }
  }
}

// ---------------- merge the two t-halves ----------------------------------
__global__ __launch_bounds__(256) void merge_halves(
    const float* __restrict__ Op0, const float* __restrict__ Op1,
    const float* __restrict__ ml, unsigned short* __restrict__ ch,
    unsigned short* __restrict__ cl) {
  int e0 = (blockIdx.x * 256 + threadIdx.x) * 4;
  int r = e0 >> 9, c = e0 & 511, h = c >> 6;
  float inv = 1.0f / (ml[(size_t)r * 8 + h] + ml[65536 + (size_t)r * 8 + h]);
  f32x4 o1 = *(const f32x4*)(Op0 + e0);
  f32x4 o2 = *(const f32x4*)(Op1 + e0);
  u16x4 hv, lv;
#pragma unroll
  for (int j = 0; j < 4; ++j) {
    float o = (o1[j] + o2[j]) * inv;
    unsigned short hh = bftr(o);
    hv[j] = hh;
    lv[j] = bftr(o - bf2f(hh));
  }
  *(u16x4*)(ch + e0) = hv;
  *(u16x4*)(cl + e0) = lv;
}

// ---------------------------------------------------------------------------
extern "C" void kernel_launch(void* const* d_in, const int* in_sizes, int n_in,
                              void* d_out, int out_size, void* d_ws,
                              size_t ws_size, hipStream_t stream) {
  const float* x = (const float*)d_in[0];
  const float* pe = (const float*)d_in[1];
  const float* ln_g = (const float*)d_in[2];
  const float* ln_b = (const float*)d_in[3];
  const float* Wq = (const float*)d_in[4];
  const float* bq = (const float*)d_in[5];
  const float* Wk = (const float*)d_in[6];
  const float* bk = (const float*)d_in[7];
  const float* Wv = (const float*)d_in[8];
  const float* bv = (const float*)d_in[9];
  const float* Wp = (const float*)d_in[10];
  const float* bp = (const float*)d_in[11];
  const float* cb = (const float*)d_in[12];
  const float* pb = (const float*)d_in[13];
  const float* Wo = (const float*)d_in[14];
  const float* bo = (const float*)d_in[15];
  float* out = (float*)d_out;

  char* ws = (char*)d_ws;
  size_t off = 0;
  auto alloc = [&](size_t bytes) -> char* {
    char* ptr = ws + off;
    off = (off + bytes + 255) & ~(size_t)255;
    return ptr;
  };
  // region A: xn hi/lo -> later Opart half 0 (fp32, same byte count)
  char* regA = alloc((size_t)2 * 8192 * 512 * 2);
  unsigned short* xn_hi = (unsigned short*)regA;
  unsigned short* xn_lo = (unsigned short*)(regA + (size_t)8192 * 512 * 2);
  float* Op0 = (float*)regA;
  // region B: pe_hi -> later Opart half 1
  char* regB = alloc((size_t)16384 * 512 * 2);
  unsigned short* pe_hi = (unsigned short*)regB;
  float* Op1 = (float*)regB;
  unsigned short* vt_hi = (unsigned short*)alloc((size_t)8192 * 512 * 2);
  unsigned short* vt_lo = (unsigned short*)alloc((size_t)8192 * 512 * 2);
  unsigned short* wqk_hi = (unsigned short*)alloc((size_t)1024 * 512 * 2);
  unsigned short* wp_hi = (unsigned short*)alloc((size_t)512 * 512 * 2);
  unsigned short* wv_hi = (unsigned short*)alloc((size_t)512 * 512 * 2);
  unsigned short* wv_lo = (unsigned short*)alloc((size_t)512 * 512 * 2);
  unsigned short* wo_hi = (unsigned short*)alloc((size_t)512 * 512 * 2);
  unsigned short* wo_lo = (unsigned short*)alloc((size_t)512 * 512 * 2);
  float* bqk = (float*)alloc(1024 * 4);
  unsigned short* qc = (unsigned short*)alloc((size_t)8192 * 512 * 2);
  unsigned short* qp = (unsigned short*)alloc((size_t)8192 * 512 * 2);
  unsigned short* kbuf = (unsigned short*)alloc((size_t)8192 * 512 * 2);
  unsigned short* pbuf = (unsigned short*)alloc((size_t)16384 * 512 * 2);
  float* mlbuf = (float*)alloc((size_t)2 * 8192 * 8 * 4);

  int nsplit = 2;
  if (ws_size < off) {
    fprintf(stderr, "kernel_launch: ws too small (need %zu, have %zu)\n", off,
            ws_size);
    return;
  }
  unsigned short* ctx_hi = (nsplit == 2) ? qc : xn_hi;
  unsigned short* ctx_lo = (nsplit == 2) ? qp : xn_lo;

  megaprep<<<17664, 256, 0, stream>>>(x, ln_g, ln_b, xn_hi, xn_lo, pe, pe_hi,
                                      Wq, Wk, Wp, Wv, Wo, bq, bk, wqk_hi,
                                      wp_hi, wv_hi, wv_lo, wo_hi, wo_lo, bqk);
  proj_all<<<1536, 256, 0, stream>>>(xn_hi, xn_lo, pe_hi, wqk_hi, wp_hi,
                                     wv_hi, wv_lo, bqk, bp, bv, cb, pb, qc,
                                     qp, kbuf, pbuf, vt_hi, vt_lo);
  flash_attn<<<1024 * nsplit, 256, 0, stream>>>(qc, qp, kbuf, pbuf, vt_hi,
                                                vt_lo, ctx_hi, ctx_lo, Op0,
                                                Op1, mlbuf, nsplit);
  if (nsplit == 2)
    merge_halves<<<4096, 256, 0, stream>>>(Op0, Op1, mlbuf, ctx_hi, ctx_lo);
  out_gemm<<<512, 256, 0, stream>>>(ctx_hi, ctx_lo, wo_hi, wo_lo, bo, out);
}

// Round 8
// 232.878 us; speedup vs baseline: 1.2827x; 1.2010x over previous
//
#include <hip/hip_runtime.h>
#include <cstdio>
#include <cstdint>

// ---------------------------------------------------------------------------
// Transformer-XL relative MHA, MI355X/gfx950.  B=16 T=512 D=512 H=8 hd=64.
// Round 8: ALL hi/lo splits dropped (measured absmax pinned at 0.0078 by the
// logit path across 7 rounds -> v/PV/out plain bf16 adds only ~0.003 rms).
// proj = 3 uniform pairs-1 128x128 GEMMs (1280 blocks); flash PV single-term,
// nsplit=1 (no merge kernel); out_gemm pairs-1. 4 launches total.
// Layouts: q/k/p/v fragment-packed (R5); LDS fragment-ordered (R6, 0 confl).
// ---------------------------------------------------------------------------

typedef short s16x8 __attribute__((ext_vector_type(8)));
typedef float f32x4 __attribute__((ext_vector_type(4)));
typedef unsigned short u16x4 __attribute__((ext_vector_type(4)));

#define CSCALE 0.1803368801111204f  // log2(e)/8

#if __has_builtin(__builtin_amdgcn_exp2f)
#define EXP2(x) __builtin_amdgcn_exp2f(x)
#else
#define EXP2(x) exp2f(x)
#endif

__device__ __forceinline__ unsigned short f2bf(float f) {  // RNE
  unsigned int u = __builtin_bit_cast(unsigned int, f);
  unsigned int r = (u + 0x7FFFu + ((u >> 16) & 1u)) >> 16;
  return (unsigned short)r;
}
__device__ __forceinline__ float bf2f(unsigned short h) {
  unsigned int u = ((unsigned int)h) << 16;
  return __builtin_bit_cast(float, u);
}

// async global->LDS, 16B/lane; LDS dest = wave-uniform base + lane*16
__device__ __forceinline__ void g2l16(const void* g, void* l) {
  __builtin_amdgcn_global_load_lds(
      (const __attribute__((address_space(1))) void*)g,
      (__attribute__((address_space(3))) void*)l, 16, 0, 0);
}

// ---------------- fused prep: ln + pe cast + weight casts ------------------
__global__ __launch_bounds__(256) void megaprep(
    const float* __restrict__ x, const float* __restrict__ g,
    const float* __restrict__ bb, unsigned short* __restrict__ xh,
    const float* __restrict__ pe, unsigned short* __restrict__ ped,
    const float* __restrict__ Wq, const float* __restrict__ Wk,
    const float* __restrict__ Wp, const float* __restrict__ Wv,
    const float* __restrict__ Wo, const float* __restrict__ bq,
    const float* __restrict__ bk, unsigned short* __restrict__ wqk,
    unsigned short* __restrict__ wpm, unsigned short* __restrict__ wvm,
    unsigned short* __restrict__ wom, float* __restrict__ bqk) {
  __shared__ float red[8];
  const int bid = blockIdx.x, tid = threadIdx.x;
  if (bid < 8192) {  // LayerNorm, one row/block
    const int wave = tid >> 6, lane = tid & 63;
    const float* xr = x + (size_t)bid * 512;
    float v0 = xr[tid], v1 = xr[tid + 256];
    float s = v0 + v1, ss = v0 * v0 + v1 * v1;
#pragma unroll
    for (int d = 1; d < 64; d <<= 1) {
      s += __shfl_xor(s, d, 64);
      ss += __shfl_xor(ss, d, 64);
    }
    if (lane == 0) { red[wave] = s; red[4 + wave] = ss; }
    __syncthreads();
    s = red[0] + red[1] + red[2] + red[3];
    ss = red[4] + red[5] + red[6] + red[7];
    const float mu = s * (1.0f / 512.0f);
    const float var = ss * (1.0f / 512.0f) - mu * mu;
    const float rstd = rsqrtf(var + 1e-5f);
#pragma unroll
    for (int i = 0; i < 2; i++) {
      int d = tid + i * 256;
      float v = (i == 0) ? v0 : v1;
      float xn = (v - mu) * rstd * g[d] + bb[d];
      xh[(size_t)bid * 512 + d] = f2bf(xn);
    }
  } else if (bid < 16384) {  // pe cast x4 (pad rows -> 0)
    int e0 = (bid - 8192) * 1024 + tid * 4;
    u16x4 o = {0, 0, 0, 0};
    if (e0 < 16368 * 512) {
      float4 v = *(const float4*)(pe + e0);
      o[0] = f2bf(v.x); o[1] = f2bf(v.y); o[2] = f2bf(v.z); o[3] = f2bf(v.w);
    }
    *(u16x4*)(ped + e0) = o;
  } else {  // weights x4, plain bf16
    int idx = (bid - 16384) * 1024 + tid * 4;
    int region = idx >> 18, off = idx & 262143;
    const float* src = (region == 0)   ? Wq
                       : (region == 1) ? Wk
                       : (region == 2) ? Wp
                       : (region == 3) ? Wv
                                       : Wo;
    float4 w = *(const float4*)(src + off);
    u16x4 hv;
    hv[0] = f2bf(w.x); hv[1] = f2bf(w.y); hv[2] = f2bf(w.z); hv[3] = f2bf(w.w);
    unsigned short* dst = (region == 0)   ? wqk
                          : (region == 1) ? wqk + 262144
                          : (region == 2) ? wpm
                          : (region == 3) ? wvm
                                          : wom;
    *(u16x4*)(dst + off) = hv;
    if (idx < 1024) {
#pragma unroll
      for (int j = 0; j < 4; j++) {
        int ii = idx + j;
        bqk[ii] = (ii < 512) ? bq[ii] : bk[ii - 512];
      }
    }
  }
}

// ---------------- 128x128 GEMM body, BK=32, pairs-1, frag-packed LDS -------
// Conflict-free: LDS holds 8+8 fragment tiles (16 rows x 32 k, lane-linear);
// every ds_read_b128 and g2l16 dest is base + lane*16.
// mode 0: fp32 O1[row*512+col] (+bias)        [out proj]
// mode 1: p packed epilogue, zero row u==1023 [p proj]
// mode 2: qc/qp packed (+cb/pb)*CSCALE col<512; k packed col>=512
// mode 3: vT packed                            [v proj]
__device__ __forceinline__ void gemm128_body(
    unsigned short* sm, int mode, int arow0, int m0e, int n0,
    const unsigned short* __restrict__ A, const unsigned short* __restrict__ B,
    const float* __restrict__ bias, void* __restrict__ O1, void* __restrict__ O2,
    void* __restrict__ O3, const float* __restrict__ cbv,
    const float* __restrict__ pbv) {
  unsigned short* bA = sm;          // 4096 shorts
  unsigned short* bB = sm + 4096;   // 4096 shorts
  const int tid = threadIdx.x, lane = tid & 63, wave = tid >> 6;
  const int wr = (wave >> 1) * 64, wc = (wave & 1) * 64;
  const int fr = lane & 15, hi2 = lane >> 4;
  const int l15 = lane & 15, lq = lane >> 4;

  f32x4 fz = {0.f, 0.f, 0.f, 0.f};
  f32x4 acc[4][4];
#pragma unroll
  for (int i = 0; i < 4; i++)
#pragma unroll
    for (int j = 0; j < 4; j++) acc[i][j] = fz;

  const unsigned short* gA0 = A + (size_t)(arow0 + wave * 32 + l15) * 512 + lq * 8;
  const unsigned short* gA1 = gA0 + 16 * 512;
  const unsigned short* gB0 = B + (size_t)(n0 + wave * 32 + l15) * 512 + lq * 8;
  const unsigned short* gB1 = gB0 + 16 * 512;
  char* dA0 = (char*)bA + wave * 2048;
  char* dA1 = dA0 + 1024;
  char* dB0 = (char*)bB + wave * 2048;
  char* dB1 = dB0 + 1024;
  const int atile = 4 * (wave >> 1), btile = 4 * (wave & 1);

  for (int k0 = 0; k0 < 512; k0 += 32) {
    __syncthreads();
    g2l16(gA0 + k0, dA0);
    g2l16(gA1 + k0, dA1);
    g2l16(gB0 + k0, dB0);
    g2l16(gB1 + k0, dB1);
    __syncthreads();
    s16x8 af[4], bf[4];
#pragma unroll
    for (int mt = 0; mt < 4; ++mt)
      af[mt] = *(const s16x8*)&bA[(atile + mt) * 512 + lane * 8];
#pragma unroll
    for (int nt = 0; nt < 4; ++nt)
      bf[nt] = *(const s16x8*)&bB[(btile + nt) * 512 + lane * 8];
#pragma unroll
    for (int mt = 0; mt < 4; ++mt)
#pragma unroll
      for (int nt = 0; nt < 4; ++nt)
        acc[mt][nt] = __builtin_amdgcn_mfma_f32_16x16x32_bf16(
            af[mt], bf[nt], acc[mt][nt], 0, 0, 0);
  }
  // epilogue: C/D layout col=lane&15, row=(lane>>4)*4+reg
#pragma unroll
  for (int nt = 0; nt < 4; ++nt) {
    int col = n0 + wc + nt * 16 + fr;
    float bval = bias[col];
#pragma unroll
    for (int mt = 0; mt < 4; ++mt) {
      int rowb_l = wr + mt * 16 + hi2 * 4;
      if (mode == 0) {
#pragma unroll
        for (int r = 0; r < 4; ++r)
          ((float*)O1)[(size_t)(m0e + rowb_l + r) * 512 + col] =
              acc[mt][nt][r] + bval;
      } else if (mode == 1) {  // p packed, zero row u==1023
        int b = m0e >> 10, u0 = m0e & 1023;
        int h = col >> 6, cc = col & 63;
        size_t cbase = (size_t)(b * 8 + h) * 64 * 1024 + (cc >> 5) * 512 +
                       ((cc & 31) >> 3) * 128 + (cc & 7);
#pragma unroll
        for (int r = 0; r < 4; ++r) {
          int u = u0 + rowb_l + r;
          float val = (u >= 1023) ? 0.f : (acc[mt][nt][r] + bval);
          ((unsigned short*)O1)[cbase + (size_t)(u >> 4) * 1024 + (u & 15) * 8] =
              f2bf(val);
        }
      } else if (mode == 2) {  // qc/qp packed (col<512), k packed (col>=512)
        int row = m0e + rowb_l;
        int b = row >> 9, s15 = row & 15, s16i = (row & 511) >> 4;
        if (col < 512) {
          int h = col >> 6, cc = col & 63;
          size_t idx = ((size_t)(b * 8 + h) * 32 + s16i) * 1024 +
                       (cc >> 5) * 512 + ((cc & 31) >> 3) * 128 + (cc & 7);
#pragma unroll
          for (int r = 0; r < 4; ++r) {
            float val = acc[mt][nt][r] + bval;
            ((unsigned short*)O1)[idx + (s15 + r) * 8] =
                f2bf((val + cbv[col]) * CSCALE);
            ((unsigned short*)O2)[idx + (s15 + r) * 8] =
                f2bf((val + pbv[col]) * CSCALE);
          }
        } else {
          int c2 = col - 512, h = c2 >> 6, cc = c2 & 63;
          size_t idx = ((size_t)(b * 8 + h) * 32 + s16i) * 1024 +
                       (cc >> 5) * 512 + ((cc & 31) >> 3) * 128 + (cc & 7);
#pragma unroll
          for (int r = 0; r < 4; ++r)
            ((unsigned short*)O3)[idx + (s15 + r) * 8] =
                f2bf(acc[mt][nt][r] + bval);
        }
      } else {  // mode 3: vT packed (rows are t, col = h*64+d)
        int rowb = m0e + rowb_l;
        int b = rowb >> 9, t = rowb & 511;
        int h = col >> 6, d = col & 63;
        size_t idx = ((size_t)((b * 8 + h) * 4 + (d >> 4)) * 16 + (t >> 5)) * 512 +
                     ((t & 31) >> 3) * 128 + (d & 15) * 8 + (t & 7);
        u16x4 hv;
#pragma unroll
        for (int r = 0; r < 4; ++r) hv[r] = f2bf(acc[mt][nt][r] + bval);
        *(u16x4*)((unsigned short*)O1 + idx) = hv;
      }
    }
  }
}

// merged projections: [0,512) qk; [512,1024) p; [1024,1280) v — all pairs-1
__global__ __launch_bounds__(256) void proj_all(
    const unsigned short* __restrict__ xn_hi, const unsigned short* __restrict__ pe_hi,
    const unsigned short* __restrict__ wqk, const unsigned short* __restrict__ wpm,
    const unsigned short* __restrict__ wvm, const float* __restrict__ bqk,
    const float* __restrict__ bp, const float* __restrict__ bv,
    const float* __restrict__ cbv, const float* __restrict__ pbv,
    unsigned short* __restrict__ qc, unsigned short* __restrict__ qp,
    unsigned short* __restrict__ kb, unsigned short* __restrict__ pbuf,
    unsigned short* __restrict__ vth) {
  __shared__ __align__(16) unsigned short sm[8192];
  const int id = blockIdx.x;
  if (id < 512) {  // qk: M=8192, N=1024
    int m0 = (id >> 3) * 128, n0 = (id & 7) * 128;
    gemm128_body(sm, 2, m0, m0, n0, xn_hi, wqk, bqk, qc, qp, kb, cbv, pbv);
  } else if (id < 1024) {  // p: per-b 1023-row A
    int l = id - 512;
    int y = l >> 2, n0 = (l & 3) * 128;
    int b = y >> 3, mt8 = y & 7;
    gemm128_body(sm, 1, b * 1023 + mt8 * 128, b * 1024 + mt8 * 128, n0, pe_hi,
                 wpm, bp, pbuf, nullptr, nullptr, nullptr, nullptr);
  } else {  // v: M=8192, N=512
    int l = id - 1024;
    int m0 = (l >> 2) * 128, n0 = (l & 3) * 128;
    gemm128_body(sm, 3, m0, m0, n0, xn_hi, wvm, bv, vth, nullptr, nullptr,
                 nullptr, nullptr);
  }
}

__global__ __launch_bounds__(256) void out_gemm(
    const unsigned short* __restrict__ ctx, const unsigned short* __restrict__ wom,
    const float* __restrict__ bo, float* __restrict__ out) {
  __shared__ __align__(16) unsigned short sm[8192];
  const int id = blockIdx.x;  // 256 blocks: 64 m-tiles x 4 n-tiles
  int m0 = (id >> 2) * 128, n0 = (id & 3) * 128;
  gemm128_body(sm, 0, m0, m0, n0, ctx, wom, bo, out, nullptr, nullptr,
               nullptr, nullptr);
}

// ---------------- barrier-free flash attention, packed fragments -----------
// grid 1024; id%128=(b,h). Wave owns 16 q-rows. Fixed-max softmax. PV plain.
__global__ __launch_bounds__(256) void flash_attn(
    const unsigned short* __restrict__ qc, const unsigned short* __restrict__ qp,
    const unsigned short* __restrict__ kb, const unsigned short* __restrict__ pm,
    const unsigned short* __restrict__ vth, unsigned short* __restrict__ ctx) {
  const int id = blockIdx.x;
  const int bh = id & 127, b = bh >> 3, h = bh & 7;
  const int s_blk = id >> 7;
  const int tid = threadIdx.x, wave = tid >> 6, lane = tid & 63;
  const int fr = lane & 15, hi2 = lane >> 4, fc = hi2 * 8;
  const int s0w = s_blk * 64 + wave * 16;
  const int crow = hi2 * 4;

  __shared__ __align__(16) unsigned short Ph_s[4][16][40];
  unsigned short(*Phw)[40] = Ph_s[wave];

  int srcl[4];
#pragma unroll
  for (int r = 0; r < 4; ++r) srcl[r] = (hi2 << 4) | ((fr - (crow + r) - 1) & 15);

  const size_t qtb = ((size_t)(b * 8 + h) * 32 + (s0w >> 4)) * 1024 + lane * 8;
  s16x8 aqc0 = *(const s16x8*)(qc + qtb);
  s16x8 aqc1 = *(const s16x8*)(qc + qtb + 512);
  s16x8 aqp0 = *(const s16x8*)(qp + qtb);
  s16x8 aqp1 = *(const s16x8*)(qp + qtb + 512);

  const unsigned short* kpk = kb + (size_t)(b * 8 + h) * 32 * 1024 + lane * 8;
  const unsigned short* ppk = pm + (size_t)(b * 8 + h) * 64 * 1024 + lane * 8;
  const unsigned short* vhk = vth + (size_t)(b * 8 + h) * 64 * 512 + lane * 8;

  f32x4 fz = {0.f, 0.f, 0.f, 0.f};
  f32x4 Oacc[4] = {fz, fz, fz, fz};
  float lsum[4] = {0.f, 0.f, 0.f, 0.f};

  for (int step = 0; step < 16; ++step) {
    const int t0 = step * 32;
    const int u0w = t0 - s0w + 496;
    const int kt = t0 >> 4, ut = u0w >> 4, vt = t0 >> 5;
    f32x4 sc[2] = {fz, fz};
#pragma unroll
    for (int nt = 0; nt < 2; ++nt) {
      const unsigned short* kr = kpk + (size_t)(kt + nt) * 1024;
      s16x8 b0 = *(const s16x8*)kr;
      s16x8 b1 = *(const s16x8*)(kr + 512);
      sc[nt] = __builtin_amdgcn_mfma_f32_16x16x32_bf16(aqc0, b0, sc[nt], 0, 0, 0);
      sc[nt] = __builtin_amdgcn_mfma_f32_16x16x32_bf16(aqc1, b1, sc[nt], 0, 0, 0);
    }
    f32x4 sp[3];
#pragma unroll
    for (int nt = 0; nt < 3; ++nt) {
      const unsigned short* pr = ppk + (size_t)(ut + nt) * 1024;
      s16x8 b0 = *(const s16x8*)pr;
      s16x8 b1 = *(const s16x8*)(pr + 512);
      f32x4 t = fz;
      t = __builtin_amdgcn_mfma_f32_16x16x32_bf16(aqp0, b0, t, 0, 0, 0);
      t = __builtin_amdgcn_mfma_f32_16x16x32_bf16(aqp1, b1, t, 0, 0, 0);
      sp[nt] = t;
    }
    float sj[3][4];
#pragma unroll
    for (int j = 0; j < 3; ++j)
#pragma unroll
      for (int r = 0; r < 4; ++r) sj[j][r] = __shfl(sp[j][r], srcl[r], 64);
#pragma unroll
    for (int nt = 0; nt < 2; ++nt) {
      int tc = nt * 16 + fr;
#pragma unroll
      for (int r = 0; r < 4; ++r) {
        float pos = (fr <= crow + r) ? sj[nt][r] : sj[nt + 1][r];
        float e = EXP2(sc[nt][r] + pos);
        lsum[r] += e;
        Phw[crow + r][tc] = f2bf(e);
      }
    }
    s16x8 ah = *(const s16x8*)&Phw[fr][fc];
#pragma unroll
    for (int nt = 0; nt < 4; ++nt) {
      s16x8 bh = *(const s16x8*)(vhk + (size_t)(nt * 16 + vt) * 512);
      Oacc[nt] = __builtin_amdgcn_mfma_f32_16x16x32_bf16(ah, bh, Oacc[nt], 0, 0, 0);
    }
  }
#pragma unroll
  for (int d = 1; d < 16; d <<= 1)
#pragma unroll
    for (int r = 0; r < 4; ++r) lsum[r] += __shfl_xor(lsum[r], d, 64);
  // epilogue: ctx bf16 [row*512 + col], row-major for the out GEMM
#pragma unroll
  for (int nt = 0; nt < 4; ++nt)
#pragma unroll
    for (int r = 0; r < 4; ++r) {
      float o = Oacc[nt][r] / lsum[r];
      size_t idx =
          (size_t)(b * 512 + s0w + crow + r) * 512 + h * 64 + nt * 16 + fr;
      ctx[idx] = f2bf(o);
    }
}

// ---------------------------------------------------------------------------
extern "C" void kernel_launch(void* const* d_in, const int* in_sizes, int n_in,
                              void* d_out, int out_size, void* d_ws,
                              size_t ws_size, hipStream_t stream) {
  const float* x = (const float*)d_in[0];
  const float* pe = (const float*)d_in[1];
  const float* ln_g = (const float*)d_in[2];
  const float* ln_b = (const float*)d_in[3];
  const float* Wq = (const float*)d_in[4];
  const float* bq = (const float*)d_in[5];
  const float* Wk = (const float*)d_in[6];
  const float* bk = (const float*)d_in[7];
  const float* Wv = (const float*)d_in[8];
  const float* bv = (const float*)d_in[9];
  const float* Wp = (const float*)d_in[10];
  const float* bp = (const float*)d_in[11];
  const float* cb = (const float*)d_in[12];
  const float* pb = (const float*)d_in[13];
  const float* Wo = (const float*)d_in[14];
  const float* bo = (const float*)d_in[15];
  float* out = (float*)d_out;

  char* ws = (char*)d_ws;
  size_t off = 0;
  auto alloc = [&](size_t bytes) -> char* {
    char* ptr = ws + off;
    off = (off + bytes + 255) & ~(size_t)255;
    return ptr;
  };
  // region A: xn (8 MB) -> reused as ctx after proj_all completes
  unsigned short* xn_hi = (unsigned short*)alloc((size_t)8192 * 512 * 2);
  unsigned short* ctx = xn_hi;  // xn dead after proj_all; flash never reads xn
  unsigned short* pe_hi = (unsigned short*)alloc((size_t)16384 * 512 * 2);
  unsigned short* vt_hi = (unsigned short*)alloc((size_t)8192 * 512 * 2);
  unsigned short* wqk = (unsigned short*)alloc((size_t)1024 * 512 * 2);
  unsigned short* wpm = (unsigned short*)alloc((size_t)512 * 512 * 2);
  unsigned short* wvm = (unsigned short*)alloc((size_t)512 * 512 * 2);
  unsigned short* wom = (unsigned short*)alloc((size_t)512 * 512 * 2);
  float* bqk = (float*)alloc(1024 * 4);
  unsigned short* qc = (unsigned short*)alloc((size_t)8192 * 512 * 2);
  unsigned short* qp = (unsigned short*)alloc((size_t)8192 * 512 * 2);
  unsigned short* kbuf = (unsigned short*)alloc((size_t)8192 * 512 * 2);
  unsigned short* pbuf = (unsigned short*)alloc((size_t)16384 * 512 * 2);

  if (ws_size < off) {
    fprintf(stderr, "kernel_launch: ws too small (need %zu, have %zu)\n", off,
            ws_size);
    return;
  }

  megaprep<<<17664, 256, 0, stream>>>(x, ln_g, ln_b, xn_hi, pe, pe_hi, Wq, Wk,
                                      Wp, Wv, Wo, bq, bk, wqk, wpm, wvm, wom,
                                      bqk);
  proj_all<<<1280, 256, 0, stream>>>(xn_hi, pe_hi, wqk, wpm, wvm, bqk, bp, bv,
                                     cb, pb, qc, qp, kbuf, pbuf, vt_hi);
  flash_attn<<<1024, 256, 0, stream>>>(qc, qp, kbuf, pbuf, vt_hi, ctx);
  out_gemm<<<256, 256, 0, stream>>>(ctx, wom, bo, out);
}

// Round 9
// 228.501 us; speedup vs baseline: 1.3072x; 1.0192x over previous
//
#include <hip/hip_runtime.h>
#include <cstdio>
#include <cstdint>

// ---------------------------------------------------------------------------
// Transformer-XL relative MHA, MI355X/gfx950.  B=16 T=512 D=512 H=8 hd=64.
// Round 9: ALL GEMMs barrier-free with fragment-packed operands and direct
// global->VGPR fragment loads (the R5 flash trick, applied to projections +
// out). megaprep packs xn/pe/weights into 16-row x 512-k fragment strips;
// flash writes ctx packed. Per wave: 64x64 tile, 8x 1KB contiguous loads +
// 16 MFMA per k-chunk, zero LDS, zero __syncthreads. R8's proj was pure
// barrier-drain (MfmaUtil 12%, all pipes idle at 68us).
// pack(r,k) = (r>>4)*8192 + (k>>5)*512 + ((k>>3)&3)*128 + (r&15)*8 + (k&7)
// Precision: plain bf16 everywhere (R8 proved absmax pinned by logit path).
// ---------------------------------------------------------------------------

typedef short s16x8 __attribute__((ext_vector_type(8)));
typedef float f32x4 __attribute__((ext_vector_type(4)));
typedef unsigned short u16x4 __attribute__((ext_vector_type(4)));

#define CSCALE 0.1803368801111204f  // log2(e)/8

#if __has_builtin(__builtin_amdgcn_exp2f)
#define EXP2(x) __builtin_amdgcn_exp2f(x)
#else
#define EXP2(x) exp2f(x)
#endif

__device__ __forceinline__ unsigned short f2bf(float f) {  // RNE
  unsigned int u = __builtin_bit_cast(unsigned int, f);
  unsigned int r = (u + 0x7FFFu + ((u >> 16) & 1u)) >> 16;
  return (unsigned short)r;
}
__device__ __forceinline__ float bf2f(unsigned short h) {
  unsigned int u = ((unsigned int)h) << 16;
  return __builtin_bit_cast(float, u);
}
// fragment-strip packing: strips of 16 rows x 512 k (8192 shorts)
__device__ __forceinline__ size_t pk(int row, int col) {
  return (size_t)(row >> 4) * 8192 + (col >> 5) * 512 + ((col >> 3) & 3) * 128 +
         (row & 15) * 8 + (col & 7);
}

// ---------------- fused prep: ln + pe cast + weight casts (all packed) -----
__global__ __launch_bounds__(256) void megaprep(
    const float* __restrict__ x, const float* __restrict__ g,
    const float* __restrict__ bb, unsigned short* __restrict__ xpk,
    const float* __restrict__ pe, unsigned short* __restrict__ pepk,
    const float* __restrict__ Wq, const float* __restrict__ Wk,
    const float* __restrict__ Wp, const float* __restrict__ Wv,
    const float* __restrict__ Wo, const float* __restrict__ bq,
    const float* __restrict__ bk, unsigned short* __restrict__ wqk,
    unsigned short* __restrict__ wpm, unsigned short* __restrict__ wvm,
    unsigned short* __restrict__ wom, float* __restrict__ bqk) {
  __shared__ float red[8];
  const int bid = blockIdx.x, tid = threadIdx.x;
  if (bid < 8192) {  // LayerNorm, one row/block -> packed xn
    const int wave = tid >> 6, lane = tid & 63;
    const float* xr = x + (size_t)bid * 512;
    float v0 = xr[tid], v1 = xr[tid + 256];
    float s = v0 + v1, ss = v0 * v0 + v1 * v1;
#pragma unroll
    for (int d = 1; d < 64; d <<= 1) {
      s += __shfl_xor(s, d, 64);
      ss += __shfl_xor(ss, d, 64);
    }
    if (lane == 0) { red[wave] = s; red[4 + wave] = ss; }
    __syncthreads();
    s = red[0] + red[1] + red[2] + red[3];
    ss = red[4] + red[5] + red[6] + red[7];
    const float mu = s * (1.0f / 512.0f);
    const float var = ss * (1.0f / 512.0f) - mu * mu;
    const float rstd = rsqrtf(var + 1e-5f);
#pragma unroll
    for (int i = 0; i < 2; i++) {
      int d = tid + i * 256;
      float v = (i == 0) ? v0 : v1;
      float xn = (v - mu) * rstd * g[d] + bb[d];
      xpk[pk(bid, d)] = f2bf(xn);
    }
  } else if (bid < 16384) {  // pe -> per-b packed strips (pad row u=1023 -> 0)
    int e = (bid - 8192) * 1024 + tid * 4;  // over 16384*512
    int r = e >> 9, c = e & 511;
    int b = r >> 10, u = r & 1023;
    u16x4 o = {0, 0, 0, 0};
    if (u < 1023) {
      float4 v = *(const float4*)(pe + (size_t)(b * 1023 + u) * 512 + c);
      o[0] = f2bf(v.x); o[1] = f2bf(v.y); o[2] = f2bf(v.z); o[3] = f2bf(v.w);
    }
    *(u16x4*)(pepk + (size_t)b * 524288 + pk(u, c)) = o;
  } else {  // weights x4 -> packed (k%4==0 -> 4 contiguous shorts in pack)
    int idx = (bid - 16384) * 1024 + tid * 4;
    int region = idx >> 18, off = idx & 262143;
    const float* src = (region == 0)   ? Wq
                       : (region == 1) ? Wk
                       : (region == 2) ? Wp
                       : (region == 3) ? Wv
                                       : Wo;
    float4 w = *(const float4*)(src + off);
    u16x4 hv;
    hv[0] = f2bf(w.x); hv[1] = f2bf(w.y); hv[2] = f2bf(w.z); hv[3] = f2bf(w.w);
    int n = off >> 9, k = off & 511;
    unsigned short* dst;
    int nrow = n;
    if (region == 0) { dst = wqk; }
    else if (region == 1) { dst = wqk; nrow = n + 512; }
    else if (region == 2) { dst = wpm; }
    else if (region == 3) { dst = wvm; }
    else { dst = wom; }
    *(u16x4*)(dst + pk(nrow, k)) = hv;
    if (idx < 1024) {
#pragma unroll
      for (int j = 0; j < 4; j++) {
        int ii = idx + j;
        bqk[ii] = (ii < 512) ? bq[ii] : bk[ii - 512];
      }
    }
  }
}

// ---------------- direct-load 64x64 GEMM core (no LDS, no barriers) --------
// acc[mt][nt] += A[64x512] @ B[64x512]^T over packed strips.
__device__ __forceinline__ void gemm64_direct(
    const unsigned short* __restrict__ Apk, const unsigned short* __restrict__ Bpk,
    int mstrip0, int nstrip0, int lane, f32x4 acc[4][4]) {
  const unsigned short* ab = Apk + (size_t)mstrip0 * 8192 + lane * 8;
  const unsigned short* bb = Bpk + (size_t)nstrip0 * 8192 + lane * 8;
#pragma unroll 4
  for (int kc = 0; kc < 16; ++kc) {
    s16x8 af[4], bf[4];
#pragma unroll
    for (int mt = 0; mt < 4; ++mt)
      af[mt] = *(const s16x8*)(ab + (size_t)mt * 8192 + kc * 512);
#pragma unroll
    for (int nt = 0; nt < 4; ++nt)
      bf[nt] = *(const s16x8*)(bb + (size_t)nt * 8192 + kc * 512);
#pragma unroll
    for (int mt = 0; mt < 4; ++mt)
#pragma unroll
      for (int nt = 0; nt < 4; ++nt)
        acc[mt][nt] = __builtin_amdgcn_mfma_f32_16x16x32_bf16(
            af[mt], bf[nt], acc[mt][nt], 0, 0, 0);
  }
}

// merged projections: wave-tiles — qk [0,2048), p [2048,4096), v [4096,5120)
__global__ __launch_bounds__(256) void proj_all(
    const unsigned short* __restrict__ xpk, const unsigned short* __restrict__ pepk,
    const unsigned short* __restrict__ wqk, const unsigned short* __restrict__ wpm,
    const unsigned short* __restrict__ wvm, const float* __restrict__ bqk,
    const float* __restrict__ bp, const float* __restrict__ bv,
    const float* __restrict__ cbv, const float* __restrict__ pbv,
    unsigned short* __restrict__ qc, unsigned short* __restrict__ qp,
    unsigned short* __restrict__ kb, unsigned short* __restrict__ pbuf,
    unsigned short* __restrict__ vth) {
  const int tid = threadIdx.x, lane = tid & 63, wave = tid >> 6;
  const int w = blockIdx.x * 4 + wave;
  const int fr = lane & 15, hi2 = lane >> 4;
  f32x4 fz = {0.f, 0.f, 0.f, 0.f};
  f32x4 acc[4][4];
#pragma unroll
  for (int i = 0; i < 4; i++)
#pragma unroll
    for (int j = 0; j < 4; j++) acc[i][j] = fz;

  if (w < 2048) {  // qk: 128 m-tiles x 16 n-tiles
    int m_t = w >> 4, n_t = w & 15;
    gemm64_direct(xpk, wqk, m_t * 4, n_t * 4, lane, acc);
    int m0 = m_t * 64, n0 = n_t * 64;
#pragma unroll
    for (int nt = 0; nt < 4; ++nt) {
      int col = n0 + nt * 16 + fr;
      float bval = bqk[col];
#pragma unroll
      for (int mt = 0; mt < 4; ++mt) {
        int row = m0 + mt * 16 + hi2 * 4;
        int b = row >> 9, s15 = row & 15, s16i = (row & 511) >> 4;
        if (col < 512) {
          int h = col >> 6, cc = col & 63;
          size_t idx = ((size_t)(b * 8 + h) * 32 + s16i) * 1024 +
                       (cc >> 5) * 512 + ((cc & 31) >> 3) * 128 + (cc & 7);
          float cbc = cbv[col], pbc = pbv[col];
#pragma unroll
          for (int r = 0; r < 4; ++r) {
            float val = acc[mt][nt][r] + bval;
            qc[idx + (s15 + r) * 8] = f2bf((val + cbc) * CSCALE);
            qp[idx + (s15 + r) * 8] = f2bf((val + pbc) * CSCALE);
          }
        } else {
          int c2 = col - 512, h = c2 >> 6, cc = c2 & 63;
          size_t idx = ((size_t)(b * 8 + h) * 32 + s16i) * 1024 +
                       (cc >> 5) * 512 + ((cc & 31) >> 3) * 128 + (cc & 7);
#pragma unroll
          for (int r = 0; r < 4; ++r)
            kb[idx + (s15 + r) * 8] = f2bf(acc[mt][nt][r] + bval);
        }
      }
    }
  } else if (w < 4096) {  // p: 256 m-tiles x 8 n-tiles (per-b packed A)
    int w2 = w - 2048;
    int m_t = w2 >> 3, n_t = w2 & 7;
    int bb_ = m_t >> 4;
    gemm64_direct(pepk + (size_t)bb_ * 524288, wpm, (m_t & 15) * 4, n_t * 4,
                  lane, acc);
    int m0e = m_t * 64, n0 = n_t * 64;
    int b = m0e >> 10, u0 = m0e & 1023;
#pragma unroll
    for (int nt = 0; nt < 4; ++nt) {
      int col = n0 + nt * 16 + fr;
      float bval = bp[col];
      int h = col >> 6, cc = col & 63;
      size_t cbase = (size_t)(b * 8 + h) * 64 * 1024 + (cc >> 5) * 512 +
                     ((cc & 31) >> 3) * 128 + (cc & 7);
#pragma unroll
      for (int mt = 0; mt < 4; ++mt) {
        int ub = u0 + mt * 16 + hi2 * 4;
#pragma unroll
        for (int r = 0; r < 4; ++r) {
          int u = ub + r;
          float val = (u >= 1023) ? 0.f : (acc[mt][nt][r] + bval);
          pbuf[cbase + (size_t)(u >> 4) * 1024 + (u & 15) * 8] = f2bf(val);
        }
      }
    }
  } else {  // v: 128 m-tiles x 8 n-tiles -> vT packed
    int w3 = w - 4096;
    int m_t = w3 >> 3, n_t = w3 & 7;
    gemm64_direct(xpk, wvm, m_t * 4, n_t * 4, lane, acc);
    int m0 = m_t * 64, n0 = n_t * 64;
#pragma unroll
    for (int nt = 0; nt < 4; ++nt) {
      int col = n0 + nt * 16 + fr;
      float bval = bv[col];
      int h = col >> 6, d = col & 63;
#pragma unroll
      for (int mt = 0; mt < 4; ++mt) {
        int rowb = m0 + mt * 16 + hi2 * 4;
        int b = rowb >> 9, t = rowb & 511;
        size_t idx = ((size_t)((b * 8 + h) * 4 + (d >> 4)) * 16 + (t >> 5)) * 512 +
                     ((t & 31) >> 3) * 128 + (d & 15) * 8 + (t & 7);
        u16x4 hv;
#pragma unroll
        for (int r = 0; r < 4; ++r) hv[r] = f2bf(acc[mt][nt][r] + bval);
        *(u16x4*)(vth + idx) = hv;
      }
    }
  }
}

__global__ __launch_bounds__(256) void out_gemm(
    const unsigned short* __restrict__ ctxpk, const unsigned short* __restrict__ wom,
    const float* __restrict__ bo, float* __restrict__ out) {
  const int tid = threadIdx.x, lane = tid & 63, wave = tid >> 6;
  const int w = blockIdx.x * 4 + wave;  // 1024 waves: 128 m x 8 n
  const int fr = lane & 15, hi2 = lane >> 4;
  int m_t = w >> 3, n_t = w & 7;
  f32x4 fz = {0.f, 0.f, 0.f, 0.f};
  f32x4 acc[4][4];
#pragma unroll
  for (int i = 0; i < 4; i++)
#pragma unroll
    for (int j = 0; j < 4; j++) acc[i][j] = fz;
  gemm64_direct(ctxpk, wom, m_t * 4, n_t * 4, lane, acc);
  int m0 = m_t * 64, n0 = n_t * 64;
#pragma unroll
  for (int nt = 0; nt < 4; ++nt) {
    int col = n0 + nt * 16 + fr;
    float bval = bo[col];
#pragma unroll
    for (int mt = 0; mt < 4; ++mt) {
      int row = m0 + mt * 16 + hi2 * 4;
#pragma unroll
      for (int r = 0; r < 4; ++r)
        out[(size_t)(row + r) * 512 + col] = acc[mt][nt][r] + bval;
    }
  }
}

// ---------------- barrier-free flash attention, packed fragments -----------
// grid 1024; id%128=(b,h). Wave owns 16 q-rows. Fixed-max softmax.
__global__ __launch_bounds__(256) void flash_attn(
    const unsigned short* __restrict__ qc, const unsigned short* __restrict__ qp,
    const unsigned short* __restrict__ kb, const unsigned short* __restrict__ pm,
    const unsigned short* __restrict__ vth, unsigned short* __restrict__ ctxpk) {
  const int id = blockIdx.x;
  const int bh = id & 127, b = bh >> 3, h = bh & 7;
  const int s_blk = id >> 7;
  const int tid = threadIdx.x, wave = tid >> 6, lane = tid & 63;
  const int fr = lane & 15, hi2 = lane >> 4, fc = hi2 * 8;
  const int s0w = s_blk * 64 + wave * 16;
  const int crow = hi2 * 4;

  __shared__ __align__(16) unsigned short Ph_s[4][16][40];
  unsigned short(*Phw)[40] = Ph_s[wave];

  int srcl[4];
#pragma unroll
  for (int r = 0; r < 4; ++r) srcl[r] = (hi2 << 4) | ((fr - (crow + r) - 1) & 15);

  const size_t qtb = ((size_t)(b * 8 + h) * 32 + (s0w >> 4)) * 1024 + lane * 8;
  s16x8 aqc0 = *(const s16x8*)(qc + qtb);
  s16x8 aqc1 = *(const s16x8*)(qc + qtb + 512);
  s16x8 aqp0 = *(const s16x8*)(qp + qtb);
  s16x8 aqp1 = *(const s16x8*)(qp + qtb + 512);

  const unsigned short* kpk = kb + (size_t)(b * 8 + h) * 32 * 1024 + lane * 8;
  const unsigned short* ppk = pm + (size_t)(b * 8 + h) * 64 * 1024 + lane * 8;
  const unsigned short* vhk = vth + (size_t)(b * 8 + h) * 64 * 512 + lane * 8;

  f32x4 fz = {0.f, 0.f, 0.f, 0.f};
  f32x4 Oacc[4] = {fz, fz, fz, fz};
  float lsum[4] = {0.f, 0.f, 0.f, 0.f};

  for (int step = 0; step < 16; ++step) {
    const int t0 = step * 32;
    const int u0w = t0 - s0w + 496;
    const int kt = t0 >> 4, ut = u0w >> 4, vt = t0 >> 5;
    f32x4 sc[2] = {fz, fz};
#pragma unroll
    for (int nt = 0; nt < 2; ++nt) {
      const unsigned short* kr = kpk + (size_t)(kt + nt) * 1024;
      s16x8 b0 = *(const s16x8*)kr;
      s16x8 b1 = *(const s16x8*)(kr + 512);
      sc[nt] = __builtin_amdgcn_mfma_f32_16x16x32_bf16(aqc0, b0, sc[nt], 0, 0, 0);
      sc[nt] = __builtin_amdgcn_mfma_f32_16x16x32_bf16(aqc1, b1, sc[nt], 0, 0, 0);
    }
    f32x4 sp[3];
#pragma unroll
    for (int nt = 0; nt < 3; ++nt) {
      const unsigned short* pr = ppk + (size_t)(ut + nt) * 1024;
      s16x8 b0 = *(const s16x8*)pr;
      s16x8 b1 = *(const s16x8*)(pr + 512);
      f32x4 t = fz;
      t = __builtin_amdgcn_mfma_f32_16x16x32_bf16(aqp0, b0, t, 0, 0, 0);
      t = __builtin_amdgcn_mfma_f32_16x16x32_bf16(aqp1, b1, t, 0, 0, 0);
      sp[nt] = t;
    }
    float sj[3][4];
#pragma unroll
    for (int j = 0; j < 3; ++j)
#pragma unroll
      for (int r = 0; r < 4; ++r) sj[j][r] = __shfl(sp[j][r], srcl[r], 64);
#pragma unroll
    for (int nt = 0; nt < 2; ++nt) {
      int tc = nt * 16 + fr;
#pragma unroll
      for (int r = 0; r < 4; ++r) {
        float pos = (fr <= crow + r) ? sj[nt][r] : sj[nt + 1][r];
        float e = EXP2(sc[nt][r] + pos);
        lsum[r] += e;
        Phw[crow + r][tc] = f2bf(e);
      }
    }
    s16x8 ah = *(const s16x8*)&Phw[fr][fc];
#pragma unroll
    for (int nt = 0; nt < 4; ++nt) {
      s16x8 bh = *(const s16x8*)(vhk + (size_t)(nt * 16 + vt) * 512);
      Oacc[nt] = __builtin_amdgcn_mfma_f32_16x16x32_bf16(ah, bh, Oacc[nt], 0, 0, 0);
    }
  }
#pragma unroll
  for (int d = 1; d < 16; d <<= 1)
#pragma unroll
    for (int r = 0; r < 4; ++r) lsum[r] += __shfl_xor(lsum[r], d, 64);
  // epilogue: ctx in packed A-fragment layout for the out GEMM
#pragma unroll
  for (int nt = 0; nt < 4; ++nt)
#pragma unroll
    for (int r = 0; r < 4; ++r) {
      float o = Oacc[nt][r] / lsum[r];
      int row = b * 512 + s0w + crow + r;
      int col = h * 64 + nt * 16 + fr;
      ctxpk[pk(row, col)] = f2bf(o);
    }
}

// ---------------------------------------------------------------------------
extern "C" void kernel_launch(void* const* d_in, const int* in_sizes, int n_in,
                              void* d_out, int out_size, void* d_ws,
                              size_t ws_size, hipStream_t stream) {
  const float* x = (const float*)d_in[0];
  const float* pe = (const float*)d_in[1];
  const float* ln_g = (const float*)d_in[2];
  const float* ln_b = (const float*)d_in[3];
  const float* Wq = (const float*)d_in[4];
  const float* bq = (const float*)d_in[5];
  const float* Wk = (const float*)d_in[6];
  const float* bk = (const float*)d_in[7];
  const float* Wv = (const float*)d_in[8];
  const float* bv = (const float*)d_in[9];
  const float* Wp = (const float*)d_in[10];
  const float* bp = (const float*)d_in[11];
  const float* cb = (const float*)d_in[12];
  const float* pb = (const float*)d_in[13];
  const float* Wo = (const float*)d_in[14];
  const float* bo = (const float*)d_in[15];
  float* out = (float*)d_out;

  char* ws = (char*)d_ws;
  size_t off = 0;
  auto alloc = [&](size_t bytes) -> char* {
    char* ptr = ws + off;
    off = (off + bytes + 255) & ~(size_t)255;
    return ptr;
  };
  // xn packed (8.4 MB) -> reused as ctx packed after proj_all completes
  unsigned short* xpk = (unsigned short*)alloc((size_t)8192 * 512 * 2);
  unsigned short* ctxpk = xpk;
  unsigned short* pepk = (unsigned short*)alloc((size_t)16384 * 512 * 2);
  unsigned short* vt_hi = (unsigned short*)alloc((size_t)8192 * 512 * 2);
  unsigned short* wqk = (unsigned short*)alloc((size_t)1024 * 512 * 2);
  unsigned short* wpm = (unsigned short*)alloc((size_t)512 * 512 * 2);
  unsigned short* wvm = (unsigned short*)alloc((size_t)512 * 512 * 2);
  unsigned short* wom = (unsigned short*)alloc((size_t)512 * 512 * 2);
  float* bqk = (float*)alloc(1024 * 4);
  unsigned short* qc = (unsigned short*)alloc((size_t)8192 * 512 * 2);
  unsigned short* qp = (unsigned short*)alloc((size_t)8192 * 512 * 2);
  unsigned short* kbuf = (unsigned short*)alloc((size_t)8192 * 512 * 2);
  unsigned short* pbuf = (unsigned short*)alloc((size_t)16384 * 512 * 2);

  if (ws_size < off) {
    fprintf(stderr, "kernel_launch: ws too small (need %zu, have %zu)\n", off,
            ws_size);
    return;
  }

  megaprep<<<17664, 256, 0, stream>>>(x, ln_g, ln_b, xpk, pe, pepk, Wq, Wk,
                                      Wp, Wv, Wo, bq, bk, wqk, wpm, wvm, wom,
                                      bqk);
  proj_all<<<1280, 256, 0, stream>>>(xpk, pepk, wqk, wpm, wvm, bqk, bp, bv,
                                     cb, pb, qc, qp, kbuf, pbuf, vt_hi);
  flash_attn<<<1024, 256, 0, stream>>>(qc, qp, kbuf, pbuf, vt_hi, ctxpk);
  out_gemm<<<256, 256, 0, stream>>>(ctxpk, wom, bo, out);
}